// Round 10
// baseline (222.553 us; speedup 1.0000x reference)
//
#include <hip/hip_runtime.h>
#include <math.h>

#define D_N 4096
#define PBW 3072
#define PPW 768
#define OFFK 1024
#define OFFV 2048
#define CATW 2048

typedef __bf16 bf16_t;
typedef __bf16 bf16x8 __attribute__((ext_vector_type(8)));
typedef __bf16 bf16x4 __attribute__((ext_vector_type(4)));
typedef float f32x4 __attribute__((ext_vector_type(4)));

__device__ __forceinline__ void gld16(const void* g, void* l) {
    __builtin_amdgcn_global_load_lds((const __attribute__((address_space(1))) unsigned int*)g,
                                     (__attribute__((address_space(3))) unsigned int*)l, 16, 0, 0);
}

// ---------------------------------------------------------------- merged prep:
// blocks [0,480): wcatT ; [480,736): WoutT ; 736: WzT+Kv ; [737,1761): ln_s
__global__ __launch_bounds__(256) void k_prep(
    const float* __restrict__ Wq, const float* __restrict__ Wk, const float* __restrict__ Wv,
    const float* __restrict__ Wqp, const float* __restrict__ Wkvp, const float* __restrict__ Wout,
    const float* __restrict__ Wb, const float* __restrict__ Wdz,
    const float* __restrict__ gz, const float* __restrict__ bz,
    const float* __restrict__ s, const float* __restrict__ g_s, const float* __restrict__ b_s,
    bf16_t* __restrict__ wcatT, bf16_t* __restrict__ WoutT,
    bf16_t* __restrict__ WzT, float* __restrict__ Kv, bf16_t* __restrict__ s_nb)
{
    __shared__ float T[64][65];
    const int bx = blockIdx.x;
    const int tid = threadIdx.x;
    if (bx < 736) {
        const float* src; int ld, coff, r0;
        bf16_t* dst; int Rdst;
        if (bx < 480) {
            int c0 = (bx % 60) * 64;
            r0 = (bx / 60) * 64;
            if (c0 < 1024)      { src = Wq;   ld = 1024; coff = c0; }
            else if (c0 < 2048) { src = Wk;   ld = 1024; coff = c0 - 1024; }
            else if (c0 < 3072) { src = Wv;   ld = 1024; coff = c0 - 2048; }
            else if (c0 < 3264) { src = Wqp;  ld = 192;  coff = c0 - 3072; }
            else                { src = Wkvp; ld = 576;  coff = c0 - 3264; }
            dst = wcatT + (size_t)c0 * 512; Rdst = 512;
        } else {
            int b = bx - 480;
            int c0 = (b & 7) * 64;
            r0 = (b >> 3) * 64;
            src = Wout; ld = 512; coff = c0;
            dst = WoutT + (size_t)c0 * 2048; Rdst = 2048;
        }
        {
            int rr = tid >> 2, cb = (tid & 3) * 16;
            const float* p = src + (size_t)(r0 + rr) * ld + coff + cb;
            #pragma unroll
            for (int i = 0; i < 4; ++i)
                *(float4*)&T[rr][cb + i * 4] = *(const float4*)(p + i * 4);
        }
        __syncthreads();
        {
            int cc = tid >> 2, rb = (tid & 3) * 16;
            bf16_t* o = dst + (size_t)cc * Rdst + r0 + rb;
            bf16x8 o0, o1;
            #pragma unroll
            for (int j = 0; j < 8; ++j) o0[j] = (bf16_t)T[rb + j][cc];
            #pragma unroll
            for (int j = 0; j < 8; ++j) o1[j] = (bf16_t)T[rb + 8 + j][cc];
            *(bf16x8*)(o) = o0;
            *(bf16x8*)(o + 8) = o1;
        }
    } else if (bx == 736) {
        for (int i = tid; i < 6144; i += 256) {
            int j = i >> 7, c = i & 127;
            float w = (j < 16) ? Wb[c * 16 + j] : Wdz[c * 32 + (j - 16)];
            WzT[i] = (bf16_t)(gz[c] * w);
        }
        if (tid < 48) {
            int j = tid;
            float acc = 0.f;
            for (int c = 0; c < 128; ++c) {
                float w = (j < 16) ? Wb[c * 16 + j] : Wdz[c * 32 + (j - 16)];
                acc += bz[c] * w;
            }
            Kv[j] = acc;
        }
    } else {
        int row = (bx - 737) * 4 + (tid >> 6);
        int lane = tid & 63;
        const float4* p = (const float4*)(s + (size_t)row * 512);
        float4 v0 = p[lane];
        float4 v1 = p[lane + 64];
        float sum = v0.x + v0.y + v0.z + v0.w + v1.x + v1.y + v1.z + v1.w;
        float sq  = v0.x*v0.x + v0.y*v0.y + v0.z*v0.z + v0.w*v0.w
                  + v1.x*v1.x + v1.y*v1.y + v1.z*v1.z + v1.w*v1.w;
        #pragma unroll
        for (int off = 1; off < 64; off <<= 1) {
            sum += __shfl_xor(sum, off);
            sq  += __shfl_xor(sq, off);
        }
        float m = sum * (1.0f / 512.0f);
        float var = sq * (1.0f / 512.0f) - m * m;
        float rs = rsqrtf(var + 1e-5f);
        int c = lane * 4;
        int c2 = 256 + lane * 4;
        bf16x4 r0, r1;
        r0[0] = (bf16_t)((v0.x - m) * rs * g_s[c+0] + b_s[c+0]);
        r0[1] = (bf16_t)((v0.y - m) * rs * g_s[c+1] + b_s[c+1]);
        r0[2] = (bf16_t)((v0.z - m) * rs * g_s[c+2] + b_s[c+2]);
        r0[3] = (bf16_t)((v0.w - m) * rs * g_s[c+3] + b_s[c+3]);
        r1[0] = (bf16_t)((v1.x - m) * rs * g_s[c2+0] + b_s[c2+0]);
        r1[1] = (bf16_t)((v1.y - m) * rs * g_s[c2+1] + b_s[c2+1]);
        r1[2] = (bf16_t)((v1.z - m) * rs * g_s[c2+2] + b_s[c2+2]);
        r1[3] = (bf16_t)((v1.w - m) * rs * g_s[c2+3] + b_s[c2+3]);
        *(bf16x4*)(s_nb + (size_t)row * 512 + c)  = r0;
        *(bf16x4*)(s_nb + (size_t)row * 512 + c2) = r1;
    }
}

// ---------------------------------------------------------------- fused: proj GEMM (960) + z LN/proj (2048)
// mapping: bx<2880: bx%3==0 -> gemm bx/3, else zid 2*(bx/3)+bx%3-1; bx>=2880 -> zid 1920+bx-2880
// zbias branch is round-9 k_zbias4 verbatim (RAW: vmcnt(8); WAR: lgkmcnt(0) before re-STAGE)
__global__ __launch_bounds__(256) void k_fused(
    const bf16_t* __restrict__ A, const bf16_t* __restrict__ BT,
    bf16_t* __restrict__ projb, float* __restrict__ projp,
    const float* __restrict__ z, const bf16_t* __restrict__ WzT, const float* __restrict__ Kv,
    float* __restrict__ biasT, bf16_t* __restrict__ pzT)
{
    __shared__ __align__(16) char smem[65536];
    const int bx = blockIdx.x;
    const int tid = threadIdx.x, lane = tid & 63, w = tid >> 6;
    int gemm_id = -1, zid = 0;
    if (bx < 2880) {
        int s3 = bx % 3, b3 = bx / 3;
        if (s3 == 0) gemm_id = b3;
        else         zid = b3 * 2 + s3 - 1;
    } else {
        zid = 1920 + (bx - 2880);
    }

    if (gemm_id >= 0) {
        // ---------------- proj GEMM branch (round-9 gemm_proj verbatim)
        bf16_t (*Asl)[32] = (bf16_t(*)[32])smem;
        bf16_t (*Bsl)[32] = (bf16_t(*)[32])(smem + 8192);
        const int row0 = (gemm_id / 30) * 128, col0 = (gemm_id % 30) * 128;
        const int wr = (w >> 1) * 64, wc = (w & 1) * 64;
        const int K = 512;
        const int sr = lane >> 2, k8 = (lane & 3) * 8;
        const bf16_t* Ab = A + (size_t)(row0 + w * 32 + sr) * K + k8;
        const bf16_t* Bb = BT + (size_t)(col0 + w * 32 + sr) * K + k8;
        f32x4 acc[4][4];
        #pragma unroll
        for (int m = 0; m < 4; ++m)
            #pragma unroll
            for (int n = 0; n < 4; ++n) acc[m][n] = (f32x4){0.f,0.f,0.f,0.f};
        for (int k0 = 0; k0 < K; k0 += 32) {
            __syncthreads();
            gld16(Ab + k0,          &Asl[w * 32][0]);
            gld16(Ab + k0 + 16 * K, &Asl[w * 32 + 16][0]);
            gld16(Bb + k0,          &Bsl[w * 32][0]);
            gld16(Bb + k0 + 16 * K, &Bsl[w * 32 + 16][0]);
            __syncthreads();
            bf16x8 af[4], bfr[4];
            #pragma unroll
            for (int m = 0; m < 4; ++m) af[m]  = *(const bf16x8*)&Asl[wr + m*16 + (lane & 15)][(lane >> 4) * 8];
            #pragma unroll
            for (int n = 0; n < 4; ++n) bfr[n] = *(const bf16x8*)&Bsl[wc + n*16 + (lane & 15)][(lane >> 4) * 8];
            #pragma unroll
            for (int m = 0; m < 4; ++m)
                #pragma unroll
                for (int n = 0; n < 4; ++n)
                    acc[m][n] = __builtin_amdgcn_mfma_f32_16x16x32_bf16(af[m], bfr[n], acc[m][n], 0, 0, 0);
        }
        if (col0 < 3072) {
            #pragma unroll
            for (int m = 0; m < 4; ++m)
                #pragma unroll
                for (int n = 0; n < 4; ++n)
                    #pragma unroll
                    for (int i = 0; i < 4; ++i)
                        projb[(size_t)(row0 + wr + m*16 + (lane >> 4)*4 + i) * PBW + col0 + wc + n*16 + (lane & 15)]
                            = (bf16_t)acc[m][n][i];
        } else {
            #pragma unroll
            for (int m = 0; m < 4; ++m)
                #pragma unroll
                for (int n = 0; n < 4; ++n)
                    #pragma unroll
                    for (int i = 0; i < 4; ++i)
                        projp[(size_t)(row0 + wr + m*16 + (lane >> 4)*4 + i) * PPW + col0 - 3072 + wc + n*16 + (lane & 15)]
                            = acc[m][n][i];
        }
        return;
    }

    // ---------------- z LN + projection branch (round-9 k_zbias4 verbatim)
    float (*zbuf)[64][128] = (float(*)[64][128])smem;
    const int r16 = lane & 15, kg = lane >> 4;
    bf16x8 bfz[3][4];
    #pragma unroll
    for (int nt = 0; nt < 3; ++nt)
        #pragma unroll
        for (int kc = 0; kc < 4; ++kc)
            bfz[nt][kc] = *(const bf16x8*)(WzT + (size_t)(nt * 16 + r16) * 128 + kc * 32 + kg * 8);
    float K0 = Kv[r16], K1 = Kv[16 + r16], K2 = Kv[32 + r16];
    asm volatile("s_waitcnt vmcnt(0)" ::: "memory");
    __builtin_amdgcn_sched_barrier(0);

    const int gid = zid * 4 + w;
    const char* zb = (const char*)z + (size_t)gid * 64 * 512;
    char* lb0 = (char*)&zbuf[0][w * 16][0];
    char* lb1 = (char*)&zbuf[1][w * 16][0];

#define STAGE(i, lb) { \
    const char* gp_ = zb + (size_t)(i) * 8192 + lane * 16; \
    _Pragma("unroll") \
    for (int c_ = 0; c_ < 8; ++c_) gld16(gp_ + c_ * 1024, (lb) + c_ * 1024); }

#define PROCESS(i, b) { \
    const float* rp = &zbuf[b][w * 16 + r16][kg * 8]; \
    float4 za[4], zc[4]; \
    float sum = 0.f, sq = 0.f; \
    _Pragma("unroll") \
    for (int kc = 0; kc < 4; ++kc) { \
        float4 a_ = *(const float4*)(rp + kc * 32); \
        float4 b_ = *(const float4*)(rp + kc * 32 + 4); \
        za[kc] = a_; zc[kc] = b_; \
        sum += a_.x + a_.y + a_.z + a_.w + b_.x + b_.y + b_.z + b_.w; \
        sq  += a_.x*a_.x + a_.y*a_.y + a_.z*a_.z + a_.w*a_.w + b_.x*b_.x + b_.y*b_.y + b_.z*b_.z + b_.w*b_.w; \
    } \
    sum += __shfl_xor(sum, 16); sq += __shfl_xor(sq, 16); \
    sum += __shfl_xor(sum, 32); sq += __shfl_xor(sq, 32); \
    float m_ = sum * (1.0f / 128.0f); \
    float rs_ = rsqrtf(sq * (1.0f / 128.0f) - m_ * m_ + 1e-5f); \
    bf16x8 af[4]; \
    _Pragma("unroll") \
    for (int kc = 0; kc < 4; ++kc) { \
        af[kc][0] = (bf16_t)((za[kc].x - m_) * rs_); \
        af[kc][1] = (bf16_t)((za[kc].y - m_) * rs_); \
        af[kc][2] = (bf16_t)((za[kc].z - m_) * rs_); \
        af[kc][3] = (bf16_t)((za[kc].w - m_) * rs_); \
        af[kc][4] = (bf16_t)((zc[kc].x - m_) * rs_); \
        af[kc][5] = (bf16_t)((zc[kc].y - m_) * rs_); \
        af[kc][6] = (bf16_t)((zc[kc].z - m_) * rs_); \
        af[kc][7] = (bf16_t)((zc[kc].w - m_) * rs_); \
    } \
    f32x4 acc0 = (f32x4){0.f,0.f,0.f,0.f}; \
    f32x4 acc1 = (f32x4){0.f,0.f,0.f,0.f}; \
    f32x4 acc2 = (f32x4){0.f,0.f,0.f,0.f}; \
    _Pragma("unroll") \
    for (int kc = 0; kc < 4; ++kc) { \
        acc0 = __builtin_amdgcn_mfma_f32_16x16x32_bf16(af[kc], bfz[0][kc], acc0, 0, 0, 0); \
        acc1 = __builtin_amdgcn_mfma_f32_16x16x32_bf16(af[kc], bfz[1][kc], acc1, 0, 0, 0); \
        acc2 = __builtin_amdgcn_mfma_f32_16x16x32_bf16(af[kc], bfz[2][kc], acc2, 0, 0, 0); \
    } \
    const int t_ = gid * 4 + (i); \
    const int rowq_ = t_ >> 3; \
    const int k0_ = ((t_ & 7) << 4) + kg * 4; \
    float4 bw = {acc0[0] + K0, acc0[1] + K0, acc0[2] + K0, acc0[3] + K0}; \
    *(float4*)&biasT[((size_t)rowq_ * 16 + r16) * 128 + k0_] = bw; \
    bf16x4 p1, p2; \
    _Pragma("unroll") \
    for (int i2 = 0; i2 < 4; ++i2) { p1[i2] = (bf16_t)(acc1[i2] + K1); p2[i2] = (bf16_t)(acc2[i2] + K2); } \
    *(bf16x4*)&pzT[((size_t)rowq_ * 32 + r16) * 128 + k0_] = p1; \
    *(bf16x4*)&pzT[((size_t)rowq_ * 32 + 16 + r16) * 128 + k0_] = p2; }

// WAR fence: all prior LDS reads must have returned before the overwriting gld16s issue
#define LDS_DRAIN asm volatile("s_waitcnt lgkmcnt(0)" ::: "memory"); __builtin_amdgcn_sched_barrier(0);

    STAGE(0, lb0);
    STAGE(1, lb1);
    asm volatile("s_waitcnt vmcnt(8)" ::: "memory");
    __builtin_amdgcn_sched_barrier(0);
    PROCESS(0, 0);
    LDS_DRAIN
    STAGE(2, lb0);
    asm volatile("s_waitcnt vmcnt(8)" ::: "memory");
    __builtin_amdgcn_sched_barrier(0);
    PROCESS(1, 1);
    LDS_DRAIN
    STAGE(3, lb1);
    asm volatile("s_waitcnt vmcnt(8)" ::: "memory");
    __builtin_amdgcn_sched_barrier(0);
    PROCESS(2, 0);
    asm volatile("s_waitcnt vmcnt(0)" ::: "memory");
    __builtin_amdgcn_sched_barrier(0);
    PROCESS(3, 1);
#undef STAGE
#undef PROCESS
#undef LDS_DRAIN
}

// ---------------------------------------------------------------- attention: one wg per (nblk, head), XCD-swizzled,
// on-the-fly point rotation; manual LDS pool with region overlays (51.8 KB -> 3 blocks/CU)
__global__ __launch_bounds__(256) void k_attn4(
    const bf16_t* __restrict__ projb, const float* __restrict__ projp,
    const float* __restrict__ biasT, const float* __restrict__ rots,
    const float* __restrict__ trans, const float* __restrict__ smask,
    const int* __restrict__ kidx, const float* __restrict__ hwraw,
    bf16_t* __restrict__ catb, bf16_t* __restrict__ Pbf)
{
    __shared__ __align__(16) char pool[51840];
    bf16_t (*Qs)[72]   = (bf16_t(*)[72])pool;
    bf16_t (*Ks)[72]   = (bf16_t(*)[72])(pool + 32 * 72 * 2);
    bf16_t (*Vt)[136]  = (bf16_t(*)[136])pool;
    float  (*att)[132] = (float(*)[132])(pool + 26112);
    bf16_t (*Ps)[136]  = (bf16_t(*)[136])(pool + 26112);
    float  (*optmp)[33]= (float(*)[33])(pool + 26112 + 8704);
    float  (*kp_s)[12] = (float(*)[12])(pool + 43008);
    float  (*qp_s)[12] = (float(*)[12])(pool + 49152);
    float*  km_s       = (float*)(pool + 50688);
    float*  qm_s       = (float*)(pool + 51200);
    int*    rows_s     = (int*)(pool + 51328);

    const int wgid = blockIdx.x;
    const int swz = (wgid & 7) * 256 + (wgid >> 3);
    const int h = swz >> 7;
    const int nblk = swz & 127;
    const int tid = threadIdx.x;
    const int lane = tid & 63;
    const int w = tid >> 6;
    const int rowq0 = nblk * 32;
    const float hw = log1pf(__expf(hwraw[h])) * 0.13608276348795434f;

    if (tid < 128) {
        int ki = kidx[nblk * 128 + tid];
        int valid = (ki >= 0 && ki < D_N);
        int rr = ki < 0 ? 0 : (ki > D_N - 1 ? D_N - 1 : ki);
        rows_s[tid] = rr;
        km_s[tid] = valid ? smask[rr] : 0.0f;
    } else if (tid < 160) {
        qm_s[tid - 128] = smask[rowq0 + tid - 128];
    }
    __syncthreads();
    // ---- Phase A: stage Q (all), k-points+rot (tid<128), qp-rot + K (tid>=128)
    {
        int q = tid >> 3, cg = (tid & 7) * 8;
        *(bf16x8*)&Qs[q][cg] = *(const bf16x8*)(projb + (size_t)(rowq0 + q) * PBW + h * 64 + cg);
    }
    float Rk[9], tk0 = 0.f, tk1 = 0.f, tk2 = 0.f;
    if (tid < 128) {
        int rr = rows_s[tid];
        const float* Rp = rots + (size_t)rr * 9;
        const float* tp = trans + (size_t)rr * 3;
        #pragma unroll
        for (int e = 0; e < 9; ++e) Rk[e] = Rp[e];
        tk0 = tp[0]; tk1 = tp[1]; tk2 = tp[2];
        const float* kp = projp + (size_t)rr * PPW + 192 + h * 36;
        float4 p0 = *(const float4*)kp;
        float4 p1 = *(const float4*)(kp + 4);
        float4 p2 = *(const float4*)(kp + 8);
        float xs[4] = {p0.x, p0.w, p1.z, p2.y};
        float ys[4] = {p0.y, p1.x, p1.w, p2.z};
        float zs[4] = {p0.z, p1.y, p2.x, p2.w};
        #pragma unroll
        for (int p = 0; p < 4; ++p) {
            kp_s[tid][p*3+0] = Rk[0]*xs[p] + Rk[1]*ys[p] + Rk[2]*zs[p] + tk0;
            kp_s[tid][p*3+1] = Rk[3]*xs[p] + Rk[4]*ys[p] + Rk[5]*zs[p] + tk1;
            kp_s[tid][p*3+2] = Rk[6]*xs[p] + Rk[7]*ys[p] + Rk[8]*zs[p] + tk2;
        }
    } else {
        int j = tid - 128;
        {
            int q = j >> 2, p = j & 3;
            const float* Rp = rots + (size_t)(rowq0 + q) * 9;
            const float* tp = trans + (size_t)(rowq0 + q) * 3;
            const float* qp = projp + (size_t)(rowq0 + q) * PPW + h * 12 + p * 3;
            float x = qp[0], y = qp[1], zc = qp[2];
            qp_s[q][p*3+0] = Rp[0]*x + Rp[1]*y + Rp[2]*zc + tp[0];
            qp_s[q][p*3+1] = Rp[3]*x + Rp[4]*y + Rp[5]*zc + tp[1];
            qp_s[q][p*3+2] = Rp[6]*x + Rp[7]*y + Rp[8]*zc + tp[2];
        }
        {
            const bf16_t* pK = projb + (size_t)rows_s[j] * PBW + OFFK + h * 64;
            #pragma unroll
            for (int u = 0; u < 8; ++u)
                *(bf16x8*)&Ks[j][u * 8] = *(const bf16x8*)(pK + u * 8);
        }
    }
    __syncthreads();
    // ---- Phase B: QK^T MFMA
    {
        #pragma unroll
        for (int j = 0; j < 4; ++j) {
            int T = w * 4 + j;
            int m = T & 1, n = T >> 1;
            f32x4 acc = (f32x4){0.f,0.f,0.f,0.f};
            #pragma unroll
            for (int kc = 0; kc < 2; ++kc) {
                bf16x8 a = *(const bf16x8*)&Qs[m*16 + (lane & 15)][kc*32 + (lane >> 4) * 8];
                bf16x8 b = *(const bf16x8*)&Ks[n*16 + (lane & 15)][kc*32 + (lane >> 4) * 8];
                acc = __builtin_amdgcn_mfma_f32_16x16x32_bf16(a, b, acc, 0, 0, 0);
            }
            #pragma unroll
            for (int i = 0; i < 4; ++i)
                att[m*16 + (lane >> 4)*4 + i][n*16 + (lane & 15)] = acc[i];
        }
    }
    __syncthreads();
    // ---- Phase C: stage V^T (tid>=128) + v-points rot->Vt (tid<128) + logit assembly
    if (tid < 128) {
        const float* vp = projp + (size_t)rows_s[tid] * PPW + 192 + h * 36 + 12;
        float4 a0 = *(const float4*)(vp);
        float4 a1 = *(const float4*)(vp + 4);
        float4 a2 = *(const float4*)(vp + 8);
        float4 a3 = *(const float4*)(vp + 12);
        float4 a4 = *(const float4*)(vp + 16);
        float4 a5 = *(const float4*)(vp + 20);
        float xs[8] = {a0.x, a0.w, a1.z, a2.y, a3.x, a3.w, a4.z, a5.y};
        float ys[8] = {a0.y, a1.x, a1.w, a2.z, a3.y, a4.x, a4.w, a5.z};
        float zs[8] = {a0.z, a1.y, a2.x, a2.w, a3.z, a4.y, a5.x, a5.w};
        #pragma unroll
        for (int p = 0; p < 8; ++p) {
            Vt[64 + p*3 + 0][tid] = (bf16_t)(Rk[0]*xs[p] + Rk[1]*ys[p] + Rk[2]*zs[p] + tk0);
            Vt[64 + p*3 + 1][tid] = (bf16_t)(Rk[3]*xs[p] + Rk[4]*ys[p] + Rk[5]*zs[p] + tk1);
            Vt[64 + p*3 + 2][tid] = (bf16_t)(Rk[6]*xs[p] + Rk[7]*ys[p] + Rk[8]*zs[p] + tk2);
        }
        {
            bf16x8 zz = {};
            *(bf16x8*)&Vt[88 + (tid & 7)][(tid >> 3) * 8] = zz;
        }
    } else {
        int krow = tid - 128;
        const bf16_t* p = projb + (size_t)rows_s[krow] * PBW + OFFV + h * 64;
        #pragma unroll
        for (int u4 = 0; u4 < 8; ++u4) {
            bf16x8 v = *(const bf16x8*)(p + u4 * 8);
            #pragma unroll
            for (int jj = 0; jj < 8; ++jj) Vt[u4 * 8 + jj][krow] = v[jj];
        }
    }
    {
        int q = tid >> 3, kg = tid & 7;
        float qp[12];
        #pragma unroll
        for (int e = 0; e < 12; ++e) qp[e] = qp_s[q][e];
        float qm = qm_s[q];
        const float* bT = biasT + ((size_t)(rowq0 + q) * 16 + h) * 128;
        #pragma unroll
        for (int j2 = 0; j2 < 16; ++j2) {
            int k = kg + j2 * 8;
            float4 k0 = *(const float4*)&kp_s[k][0];
            float4 k1 = *(const float4*)&kp_s[k][4];
            float4 k2 = *(const float4*)&kp_s[k][8];
            float d0 = qp[0]-k0.x, d1 = qp[1]-k0.y, d2_ = qp[2]-k0.z, d3 = qp[3]-k0.w;
            float d4 = qp[4]-k1.x, d5 = qp[5]-k1.y, d6 = qp[6]-k1.z, d7 = qp[7]-k1.w;
            float d8 = qp[8]-k2.x, d9 = qp[9]-k2.y, d10 = qp[10]-k2.z, d11 = qp[11]-k2.w;
            float dd = d0*d0+d1*d1+d2_*d2_+d3*d3+d4*d4+d5*d5+d6*d6+d7*d7+d8*d8+d9*d9+d10*d10+d11*d11;
            float val = att[q][k] * 0.07216878364870323f
                      + 0.5773502691896258f * bT[k]
                      + 100000.0f * (qm * km_s[k] - 1.0f)
                      - 0.5f * hw * dd;
            att[q][k] = val;
        }
    }
    __syncthreads();
    // ---- Phase D: softmax; then (after barrier, att dead) write P into overlaid Ps region + global
    {
        int q = tid >> 3, kg = tid & 7;
        float l[16];
        #pragma unroll
        for (int j2 = 0; j2 < 16; ++j2) l[j2] = att[q][kg + j2 * 8];
        float mx = l[0];
        #pragma unroll
        for (int j2 = 1; j2 < 16; ++j2) mx = fmaxf(mx, l[j2]);
        mx = fmaxf(mx, __shfl_xor(mx, 1));
        mx = fmaxf(mx, __shfl_xor(mx, 2));
        mx = fmaxf(mx, __shfl_xor(mx, 4));
        float se = 0.f;
        #pragma unroll
        for (int j2 = 0; j2 < 16; ++j2) { l[j2] = __expf(l[j2] - mx); se += l[j2]; }
        se += __shfl_xor(se, 1);
        se += __shfl_xor(se, 2);
        se += __shfl_xor(se, 4);
        float inv = 1.0f / se;
        __syncthreads();   // all att reads complete before Ps (same bytes) is written
        bf16_t* pg = Pbf + ((size_t)(rowq0 + q) * 16 + h) * 128;
        #pragma unroll
        for (int j2 = 0; j2 < 16; ++j2) {
            bf16_t pb = (bf16_t)(l[j2] * inv);
            Ps[q][kg + j2 * 8] = pb;
            pg[kg + j2 * 8] = pb;
        }
    }
    __syncthreads();
    // ---- Phase E: PV MFMA
    {
        #pragma unroll
        for (int j = 0; j < 3; ++j) {
            int T = w * 3 + j;
            int m = T & 1, n = T >> 1;
            f32x4 acc = (f32x4){0.f,0.f,0.f,0.f};
            #pragma unroll
            for (int kc = 0; kc < 4; ++kc) {
                bf16x8 a = *(const bf16x8*)&Ps[m*16 + (lane & 15)][kc*32 + (lane >> 4) * 8];
                bf16x8 b = *(const bf16x8*)&Vt[n*16 + (lane & 15)][kc*32 + (lane >> 4) * 8];
                acc = __builtin_amdgcn_mfma_f32_16x16x32_bf16(a, b, acc, 0, 0, 0);
            }
            int rowb = m * 16 + (lane >> 4) * 4;
            int col = lane & 15;
            if (n < 4) {
                #pragma unroll
                for (int i = 0; i < 4; ++i)
                    catb[(size_t)(rowq0 + rowb + i) * CATW + h * 64 + n * 16 + col] = (bf16_t)acc[i];
            } else {
                #pragma unroll
                for (int i = 0; i < 4; ++i)
                    optmp[rowb + i][(n - 4) * 16 + col] = acc[i];
            }
        }
    }
    __syncthreads();
    // ---- Phase F: o_pt inverse transform + norm
    {
        int q = tid >> 3, pp = tid & 7;
        float sx = optmp[q][pp * 3 + 0];
        float sy = optmp[q][pp * 3 + 1];
        float sz = optmp[q][pp * 3 + 2];
        const float* R = rots + (size_t)(rowq0 + q) * 9;
        const float* t = trans + (size_t)(rowq0 + q) * 3;
        float x = sx - t[0], y = sy - t[1], z2 = sz - t[2];
        float ox = R[0] * x + R[3] * y + R[6] * z2;
        float oy = R[1] * x + R[4] * y + R[7] * z2;
        float oz = R[2] * x + R[5] * y + R[8] * z2;
        bf16_t* cp = catb + (size_t)(rowq0 + q) * CATW;
        cp[1024 + h * 24 + pp * 3 + 0] = (bf16_t)ox;
        cp[1024 + h * 24 + pp * 3 + 1] = (bf16_t)oy;
        cp[1024 + h * 24 + pp * 3 + 2] = (bf16_t)oz;
        cp[1408 + h * 8 + pp] = (bf16_t)sqrtf(ox * ox + oy * oy + oz * oz + 1e-8f);
    }
}

// ---------------------------------------------------------------- o_pair: per rowq MFMA [16h x 128k] x [128k x 32c]
__global__ __launch_bounds__(256) void k_opair(const bf16_t* __restrict__ Pbf,
    const bf16_t* __restrict__ pzT, bf16_t* __restrict__ catb)
{
    int tid = threadIdx.x, lane = tid & 63, w = tid >> 6;
    size_t rowq = (size_t)blockIdx.x * 4 + w;
    const bf16_t* Pp = Pbf + rowq * 2048;
    const bf16_t* zp = pzT + rowq * 4096;
    bf16x8 pa[4];
    #pragma unroll
    for (int kc = 0; kc < 4; ++kc)
        pa[kc] = *(const bf16x8*)(Pp + (size_t)(lane & 15) * 128 + kc * 32 + (lane >> 4) * 8);
    #pragma unroll
    for (int ct = 0; ct < 2; ++ct) {
        f32x4 acc = (f32x4){0.f,0.f,0.f,0.f};
        #pragma unroll
        for (int kc = 0; kc < 4; ++kc) {
            bf16x8 b = *(const bf16x8*)(zp + (size_t)(ct * 16 + (lane & 15)) * 128 + kc * 32 + (lane >> 4) * 8);
            acc = __builtin_amdgcn_mfma_f32_16x16x32_bf16(pa[kc], b, acc, 0, 0, 0);
        }
        #pragma unroll
        for (int i = 0; i < 4; ++i) {
            int hh = (lane >> 4) * 4 + i;
            catb[rowq * CATW + 1536 + hh * 32 + ct * 16 + (lane & 15)] = (bf16_t)acc[i];
        }
    }
}

// ---------------------------------------------------------------- out GEMM, 64x128 tile (256 wgs), gld16 staging
__global__ __launch_bounds__(256) void gemm_out(const bf16_t* __restrict__ A, const bf16_t* __restrict__ BT,
    float* __restrict__ C)
{
    __shared__ bf16_t Asl[64][32];
    __shared__ bf16_t Bsl[128][32];
    const int tid = threadIdx.x, lane = tid & 63, w = tid >> 6;
    const int row0 = blockIdx.y * 64, col0 = blockIdx.x * 128;
    const int wr = (w >> 1) * 32, wc = (w & 1) * 64;
    const int K = 2048;
    const int sr = lane >> 2, k8 = (lane & 3) * 8;
    const bf16_t* Ab = A + (size_t)(row0 + w * 16 + sr) * K + k8;
    const bf16_t* Bb = BT + (size_t)(col0 + w * 32 + sr) * K + k8;
    f32x4 acc[2][4];
    #pragma unroll
    for (int m = 0; m < 2; ++m)
        #pragma unroll
        for (int n = 0; n < 4; ++n) acc[m][n] = (f32x4){0.f,0.f,0.f,0.f};
    for (int k0 = 0; k0 < K; k0 += 32) {
        __syncthreads();
        gld16(Ab + k0,          &Asl[w * 16][0]);
        gld16(Bb + k0,          &Bsl[w * 32][0]);
        gld16(Bb + k0 + 16 * K, &Bsl[w * 32 + 16][0]);
        __syncthreads();
        bf16x8 af[2], bfr[4];
        #pragma unroll
        for (int m = 0; m < 2; ++m) af[m]  = *(const bf16x8*)&Asl[wr + m*16 + (lane & 15)][(lane >> 4) * 8];
        #pragma unroll
        for (int n = 0; n < 4; ++n) bfr[n] = *(const bf16x8*)&Bsl[wc + n*16 + (lane & 15)][(lane >> 4) * 8];
        #pragma unroll
        for (int m = 0; m < 2; ++m)
            #pragma unroll
            for (int n = 0; n < 4; ++n)
                acc[m][n] = __builtin_amdgcn_mfma_f32_16x16x32_bf16(af[m], bfr[n], acc[m][n], 0, 0, 0);
    }
    #pragma unroll
    for (int m = 0; m < 2; ++m)
        #pragma unroll
        for (int n = 0; n < 4; ++n)
            #pragma unroll
            for (int i = 0; i < 4; ++i)
                C[(size_t)(row0 + wr + m*16 + (lane >> 4)*4 + i) * 512 + col0 + wc + n*16 + (lane & 15)] = acc[m][n][i];
}

// ---------------------------------------------------------------- launcher
extern "C" void kernel_launch(void* const* d_in, const int* in_sizes, int n_in,
                              void* d_out, int out_size, void* d_ws, size_t ws_size,
                              hipStream_t stream)
{
    (void)in_sizes; (void)n_in; (void)out_size;
    const float* s     = (const float*)d_in[0];
    const float* z     = (const float*)d_in[1];
    const float* trans = (const float*)d_in[2];
    const float* rots  = (const float*)d_in[3];
    const float* smask = (const float*)d_in[4];
    const int*   kidx  = (const int*)d_in[5];
    const float* Wq    = (const float*)d_in[6];
    const float* Wk    = (const float*)d_in[7];
    const float* Wv    = (const float*)d_in[8];
    const float* Wqp   = (const float*)d_in[9];
    const float* Wkvp  = (const float*)d_in[10];
    const float* Wb    = (const float*)d_in[11];
    const float* Wdz   = (const float*)d_in[12];
    const float* hw    = (const float*)d_in[13];
    const float* Wout  = (const float*)d_in[14];
    const float* g_s   = (const float*)d_in[15];
    const float* b_s   = (const float*)d_in[16];
    const float* g_z   = (const float*)d_in[17];
    const float* b_z   = (const float*)d_in[18];

    char* ws = (char*)d_ws;
    bf16_t* projb = (bf16_t*)(ws);                      // 25,165,824
    float*  projp = (float*)(ws + 25165824);            // 12,582,912
    float*  biasT = (float*)(ws + 37748736);            // 33,554,432
    bf16_t* wcatT = (bf16_t*)(ws + 71303168);           //  3,932,160
    bf16_t* s_nb  = (bf16_t*)(ws + 75235328);           //  4,194,304
    bf16_t* pzT   = (bf16_t*)(ws + 79429632);           // 33,554,432
    bf16_t* Pbf   = (bf16_t*)(ws + 112984064);          // 16,777,216
    bf16_t* catb  = (bf16_t*)(ws + 129761280);          // 16,777,216
    bf16_t* WoutT = (bf16_t*)(ws + 146538496);          //  2,097,152
    bf16_t* WzT   = (bf16_t*)(ws + 148635648);          //     12,288
    float*  Kv    = (float*)(ws + 148647936);           //        192
    if (ws_size < (size_t)148648128) return;
    float* out = (float*)d_out;

    k_prep<<<1761, 256, 0, stream>>>(Wq, Wk, Wv, Wqp, Wkvp, Wout, Wb, Wdz, g_z, b_z,
                                     s, g_s, b_s, wcatT, WoutT, WzT, Kv, s_nb);
    k_fused<<<3008, 256, 0, stream>>>(s_nb, wcatT, projb, projp, z, WzT, Kv, biasT, pzT);
    k_attn4<<<2048, 256, 0, stream>>>(projb, projp, biasT, rots, trans, smask, kidx, hw, catb, Pbf);
    k_opair<<<1024, 256, 0, stream>>>(Pbf, pzT, catb);
    gemm_out<<<dim3(4, 64), 256, 0, stream>>>(catb, WoutT, out);
}

// Round 11
// 210.639 us; speedup vs baseline: 1.0566x; 1.0566x over previous
//
#include <hip/hip_runtime.h>
#include <math.h>

#define D_N 4096
#define PBW 3072
#define PPW 768
#define OFFK 1024
#define OFFV 2048
#define CATW 2048

typedef __bf16 bf16_t;
typedef __bf16 bf16x8 __attribute__((ext_vector_type(8)));
typedef __bf16 bf16x4 __attribute__((ext_vector_type(4)));
typedef float f32x4 __attribute__((ext_vector_type(4)));

__device__ __forceinline__ void gld16(const void* g, void* l) {
    __builtin_amdgcn_global_load_lds((const __attribute__((address_space(1))) unsigned int*)g,
                                     (__attribute__((address_space(3))) unsigned int*)l, 16, 0, 0);
}

// ---------------------------------------------------------------- merged prep:
// blocks [0,480): wcatT ; [480,736): WoutT ; 736: WzT+Kv ; [737,1761): ln_s
__global__ __launch_bounds__(256) void k_prep(
    const float* __restrict__ Wq, const float* __restrict__ Wk, const float* __restrict__ Wv,
    const float* __restrict__ Wqp, const float* __restrict__ Wkvp, const float* __restrict__ Wout,
    const float* __restrict__ Wb, const float* __restrict__ Wdz,
    const float* __restrict__ gz, const float* __restrict__ bz,
    const float* __restrict__ s, const float* __restrict__ g_s, const float* __restrict__ b_s,
    bf16_t* __restrict__ wcatT, bf16_t* __restrict__ WoutT,
    bf16_t* __restrict__ WzT, float* __restrict__ Kv, bf16_t* __restrict__ s_nb)
{
    __shared__ float T[64][65];
    const int bx = blockIdx.x;
    const int tid = threadIdx.x;
    if (bx < 736) {
        const float* src; int ld, coff, r0;
        bf16_t* dst; int Rdst;
        if (bx < 480) {
            int c0 = (bx % 60) * 64;
            r0 = (bx / 60) * 64;
            if (c0 < 1024)      { src = Wq;   ld = 1024; coff = c0; }
            else if (c0 < 2048) { src = Wk;   ld = 1024; coff = c0 - 1024; }
            else if (c0 < 3072) { src = Wv;   ld = 1024; coff = c0 - 2048; }
            else if (c0 < 3264) { src = Wqp;  ld = 192;  coff = c0 - 3072; }
            else                { src = Wkvp; ld = 576;  coff = c0 - 3264; }
            dst = wcatT + (size_t)c0 * 512; Rdst = 512;
        } else {
            int b = bx - 480;
            int c0 = (b & 7) * 64;
            r0 = (b >> 3) * 64;
            src = Wout; ld = 512; coff = c0;
            dst = WoutT + (size_t)c0 * 2048; Rdst = 2048;
        }
        {
            int rr = tid >> 2, cb = (tid & 3) * 16;
            const float* p = src + (size_t)(r0 + rr) * ld + coff + cb;
            #pragma unroll
            for (int i = 0; i < 4; ++i)
                *(float4*)&T[rr][cb + i * 4] = *(const float4*)(p + i * 4);
        }
        __syncthreads();
        {
            int cc = tid >> 2, rb = (tid & 3) * 16;
            bf16_t* o = dst + (size_t)cc * Rdst + r0 + rb;
            bf16x8 o0, o1;
            #pragma unroll
            for (int j = 0; j < 8; ++j) o0[j] = (bf16_t)T[rb + j][cc];
            #pragma unroll
            for (int j = 0; j < 8; ++j) o1[j] = (bf16_t)T[rb + 8 + j][cc];
            *(bf16x8*)(o) = o0;
            *(bf16x8*)(o + 8) = o1;
        }
    } else if (bx == 736) {
        for (int i = tid; i < 6144; i += 256) {
            int j = i >> 7, c = i & 127;
            float w = (j < 16) ? Wb[c * 16 + j] : Wdz[c * 32 + (j - 16)];
            WzT[i] = (bf16_t)(gz[c] * w);
        }
        if (tid < 48) {
            int j = tid;
            float acc = 0.f;
            for (int c = 0; c < 128; ++c) {
                float w = (j < 16) ? Wb[c * 16 + j] : Wdz[c * 32 + (j - 16)];
                acc += bz[c] * w;
            }
            Kv[j] = acc;
        }
    } else {
        int row = (bx - 737) * 4 + (tid >> 6);
        int lane = tid & 63;
        const float4* p = (const float4*)(s + (size_t)row * 512);
        float4 v0 = p[lane];
        float4 v1 = p[lane + 64];
        float sum = v0.x + v0.y + v0.z + v0.w + v1.x + v1.y + v1.z + v1.w;
        float sq  = v0.x*v0.x + v0.y*v0.y + v0.z*v0.z + v0.w*v0.w
                  + v1.x*v1.x + v1.y*v1.y + v1.z*v1.z + v1.w*v1.w;
        #pragma unroll
        for (int off = 1; off < 64; off <<= 1) {
            sum += __shfl_xor(sum, off);
            sq  += __shfl_xor(sq, off);
        }
        float m = sum * (1.0f / 512.0f);
        float var = sq * (1.0f / 512.0f) - m * m;
        float rs = rsqrtf(var + 1e-5f);
        int c = lane * 4;
        int c2 = 256 + lane * 4;
        bf16x4 r0, r1;
        r0[0] = (bf16_t)((v0.x - m) * rs * g_s[c+0] + b_s[c+0]);
        r0[1] = (bf16_t)((v0.y - m) * rs * g_s[c+1] + b_s[c+1]);
        r0[2] = (bf16_t)((v0.z - m) * rs * g_s[c+2] + b_s[c+2]);
        r0[3] = (bf16_t)((v0.w - m) * rs * g_s[c+3] + b_s[c+3]);
        r1[0] = (bf16_t)((v1.x - m) * rs * g_s[c2+0] + b_s[c2+0]);
        r1[1] = (bf16_t)((v1.y - m) * rs * g_s[c2+1] + b_s[c2+1]);
        r1[2] = (bf16_t)((v1.z - m) * rs * g_s[c2+2] + b_s[c2+2]);
        r1[3] = (bf16_t)((v1.w - m) * rs * g_s[c2+3] + b_s[c2+3]);
        *(bf16x4*)(s_nb + (size_t)row * 512 + c)  = r0;
        *(bf16x4*)(s_nb + (size_t)row * 512 + c2) = r1;
    }
}

// ---------------------------------------------------------------- fused: proj GEMM (960 blocks, 16KB LDS) +
// z LN/proj (2048 blocks, REGISTER-resident, zero LDS, no manual waitcnt)
// mapping: bx<2880: bx%3==0 -> gemm bx/3, else zid 2*(bx/3)+bx%3-1; bx>=2880 -> zid 1920+bx-2880
__global__ __launch_bounds__(256) void k_fused(
    const bf16_t* __restrict__ A, const bf16_t* __restrict__ BT,
    bf16_t* __restrict__ projb, float* __restrict__ projp,
    const float* __restrict__ z, const bf16_t* __restrict__ WzT, const float* __restrict__ Kv,
    float* __restrict__ biasT, bf16_t* __restrict__ pzT)
{
    __shared__ bf16_t Asl[128][32];
    __shared__ bf16_t Bsl[128][32];
    const int bx = blockIdx.x;
    const int tid = threadIdx.x, lane = tid & 63, w = tid >> 6;
    int gemm_id = -1, zid = 0;
    if (bx < 2880) {
        int s3 = bx % 3, b3 = bx / 3;
        if (s3 == 0) gemm_id = b3;
        else         zid = b3 * 2 + s3 - 1;
    } else {
        zid = 1920 + (bx - 2880);
    }

    if (gemm_id >= 0) {
        // ---------------- proj GEMM branch (round-9/10 verbatim)
        const int row0 = (gemm_id / 30) * 128, col0 = (gemm_id % 30) * 128;
        const int wr = (w >> 1) * 64, wc = (w & 1) * 64;
        const int K = 512;
        const int sr = lane >> 2, k8 = (lane & 3) * 8;
        const bf16_t* Ab = A + (size_t)(row0 + w * 32 + sr) * K + k8;
        const bf16_t* Bb = BT + (size_t)(col0 + w * 32 + sr) * K + k8;
        f32x4 acc[4][4];
        #pragma unroll
        for (int m = 0; m < 4; ++m)
            #pragma unroll
            for (int n = 0; n < 4; ++n) acc[m][n] = (f32x4){0.f,0.f,0.f,0.f};
        for (int k0 = 0; k0 < K; k0 += 32) {
            __syncthreads();
            gld16(Ab + k0,          &Asl[w * 32][0]);
            gld16(Ab + k0 + 16 * K, &Asl[w * 32 + 16][0]);
            gld16(Bb + k0,          &Bsl[w * 32][0]);
            gld16(Bb + k0 + 16 * K, &Bsl[w * 32 + 16][0]);
            __syncthreads();
            bf16x8 af[4], bfr[4];
            #pragma unroll
            for (int m = 0; m < 4; ++m) af[m]  = *(const bf16x8*)&Asl[wr + m*16 + (lane & 15)][(lane >> 4) * 8];
            #pragma unroll
            for (int n = 0; n < 4; ++n) bfr[n] = *(const bf16x8*)&Bsl[wc + n*16 + (lane & 15)][(lane >> 4) * 8];
            #pragma unroll
            for (int m = 0; m < 4; ++m)
                #pragma unroll
                for (int n = 0; n < 4; ++n)
                    acc[m][n] = __builtin_amdgcn_mfma_f32_16x16x32_bf16(af[m], bfr[n], acc[m][n], 0, 0, 0);
        }
        if (col0 < 3072) {
            #pragma unroll
            for (int m = 0; m < 4; ++m)
                #pragma unroll
                for (int n = 0; n < 4; ++n)
                    #pragma unroll
                    for (int i = 0; i < 4; ++i)
                        projb[(size_t)(row0 + wr + m*16 + (lane >> 4)*4 + i) * PBW + col0 + wc + n*16 + (lane & 15)]
                            = (bf16_t)acc[m][n][i];
        } else {
            #pragma unroll
            for (int m = 0; m < 4; ++m)
                #pragma unroll
                for (int n = 0; n < 4; ++n)
                    #pragma unroll
                    for (int i = 0; i < 4; ++i)
                        projp[(size_t)(row0 + wr + m*16 + (lane >> 4)*4 + i) * PPW + col0 - 3072 + wc + n*16 + (lane & 15)]
                            = acc[m][n][i];
        }
        return;
    }

    // ---------------- z LN + projection branch: register-resident, compiler-managed waits
    const int r16 = lane & 15, kg = lane >> 4;
    bf16x8 bfz[3][4];
    #pragma unroll
    for (int nt = 0; nt < 3; ++nt)
        #pragma unroll
        for (int kc = 0; kc < 4; ++kc)
            bfz[nt][kc] = *(const bf16x8*)(WzT + (size_t)(nt * 16 + r16) * 128 + kc * 32 + kg * 8);
    const float K0 = Kv[r16], K1 = Kv[16 + r16], K2 = Kv[32 + r16];
    const int gid = zid * 4 + w;

    #pragma unroll 2
    for (int it = 0; it < 4; ++it) {
        const int t_ = gid * 4 + it;                 // tile index, rows t_*16 .. +16
        const float* zp = z + ((size_t)t_ * 16 + r16) * 128 + kg * 8;
        float4 za[4], zc[4];
        float sum = 0.f, sq = 0.f;
        #pragma unroll
        for (int kc = 0; kc < 4; ++kc) {
            za[kc] = *(const float4*)(zp + kc * 32);
            zc[kc] = *(const float4*)(zp + kc * 32 + 4);
            sum += za[kc].x + za[kc].y + za[kc].z + za[kc].w + zc[kc].x + zc[kc].y + zc[kc].z + zc[kc].w;
            sq  += za[kc].x*za[kc].x + za[kc].y*za[kc].y + za[kc].z*za[kc].z + za[kc].w*za[kc].w
                 + zc[kc].x*zc[kc].x + zc[kc].y*zc[kc].y + zc[kc].z*zc[kc].z + zc[kc].w*zc[kc].w;
        }
        sum += __shfl_xor(sum, 16); sq += __shfl_xor(sq, 16);
        sum += __shfl_xor(sum, 32); sq += __shfl_xor(sq, 32);
        float m_ = sum * (1.0f / 128.0f);
        float rs_ = rsqrtf(sq * (1.0f / 128.0f) - m_ * m_ + 1e-5f);
        bf16x8 af[4];
        #pragma unroll
        for (int kc = 0; kc < 4; ++kc) {
            af[kc][0] = (bf16_t)((za[kc].x - m_) * rs_);
            af[kc][1] = (bf16_t)((za[kc].y - m_) * rs_);
            af[kc][2] = (bf16_t)((za[kc].z - m_) * rs_);
            af[kc][3] = (bf16_t)((za[kc].w - m_) * rs_);
            af[kc][4] = (bf16_t)((zc[kc].x - m_) * rs_);
            af[kc][5] = (bf16_t)((zc[kc].y - m_) * rs_);
            af[kc][6] = (bf16_t)((zc[kc].z - m_) * rs_);
            af[kc][7] = (bf16_t)((zc[kc].w - m_) * rs_);
        }
        f32x4 acc0 = (f32x4){0.f,0.f,0.f,0.f};
        f32x4 acc1 = (f32x4){0.f,0.f,0.f,0.f};
        f32x4 acc2 = (f32x4){0.f,0.f,0.f,0.f};
        #pragma unroll
        for (int kc = 0; kc < 4; ++kc) {
            acc0 = __builtin_amdgcn_mfma_f32_16x16x32_bf16(af[kc], bfz[0][kc], acc0, 0, 0, 0);
            acc1 = __builtin_amdgcn_mfma_f32_16x16x32_bf16(af[kc], bfz[1][kc], acc1, 0, 0, 0);
            acc2 = __builtin_amdgcn_mfma_f32_16x16x32_bf16(af[kc], bfz[2][kc], acc2, 0, 0, 0);
        }
        const int rowq_ = t_ >> 3;
        const int k0_ = ((t_ & 7) << 4) + kg * 4;
        float4 bw = {acc0[0] + K0, acc0[1] + K0, acc0[2] + K0, acc0[3] + K0};
        *(float4*)&biasT[((size_t)rowq_ * 16 + r16) * 128 + k0_] = bw;
        bf16x4 p1, p2;
        #pragma unroll
        for (int i2 = 0; i2 < 4; ++i2) { p1[i2] = (bf16_t)(acc1[i2] + K1); p2[i2] = (bf16_t)(acc2[i2] + K2); }
        *(bf16x4*)&pzT[((size_t)rowq_ * 32 + r16) * 128 + k0_] = p1;
        *(bf16x4*)&pzT[((size_t)rowq_ * 32 + 16 + r16) * 128 + k0_] = p2;
    }
}

// ---------------------------------------------------------------- attention: one wg per (nblk, head), XCD-swizzled,
// on-the-fly point rotation; manual LDS pool with region overlays (51.8 KB -> 3 blocks/CU)
__global__ __launch_bounds__(256) void k_attn4(
    const bf16_t* __restrict__ projb, const float* __restrict__ projp,
    const float* __restrict__ biasT, const float* __restrict__ rots,
    const float* __restrict__ trans, const float* __restrict__ smask,
    const int* __restrict__ kidx, const float* __restrict__ hwraw,
    bf16_t* __restrict__ catb, bf16_t* __restrict__ Pbf)
{
    __shared__ __align__(16) char pool[51840];
    bf16_t (*Qs)[72]   = (bf16_t(*)[72])pool;
    bf16_t (*Ks)[72]   = (bf16_t(*)[72])(pool + 32 * 72 * 2);
    bf16_t (*Vt)[136]  = (bf16_t(*)[136])pool;
    float  (*att)[132] = (float(*)[132])(pool + 26112);
    bf16_t (*Ps)[136]  = (bf16_t(*)[136])(pool + 26112);
    float  (*optmp)[33]= (float(*)[33])(pool + 26112 + 8704);
    float  (*kp_s)[12] = (float(*)[12])(pool + 43008);
    float  (*qp_s)[12] = (float(*)[12])(pool + 49152);
    float*  km_s       = (float*)(pool + 50688);
    float*  qm_s       = (float*)(pool + 51200);
    int*    rows_s     = (int*)(pool + 51328);

    const int wgid = blockIdx.x;
    const int swz = (wgid & 7) * 256 + (wgid >> 3);
    const int h = swz >> 7;
    const int nblk = swz & 127;
    const int tid = threadIdx.x;
    const int lane = tid & 63;
    const int w = tid >> 6;
    const int rowq0 = nblk * 32;
    const float hw = log1pf(__expf(hwraw[h])) * 0.13608276348795434f;

    if (tid < 128) {
        int ki = kidx[nblk * 128 + tid];
        int valid = (ki >= 0 && ki < D_N);
        int rr = ki < 0 ? 0 : (ki > D_N - 1 ? D_N - 1 : ki);
        rows_s[tid] = rr;
        km_s[tid] = valid ? smask[rr] : 0.0f;
    } else if (tid < 160) {
        qm_s[tid - 128] = smask[rowq0 + tid - 128];
    }
    __syncthreads();
    // ---- Phase A: stage Q (all), k-points+rot (tid<128), qp-rot + K (tid>=128)
    {
        int q = tid >> 3, cg = (tid & 7) * 8;
        *(bf16x8*)&Qs[q][cg] = *(const bf16x8*)(projb + (size_t)(rowq0 + q) * PBW + h * 64 + cg);
    }
    float Rk[9], tk0 = 0.f, tk1 = 0.f, tk2 = 0.f;
    if (tid < 128) {
        int rr = rows_s[tid];
        const float* Rp = rots + (size_t)rr * 9;
        const float* tp = trans + (size_t)rr * 3;
        #pragma unroll
        for (int e = 0; e < 9; ++e) Rk[e] = Rp[e];
        tk0 = tp[0]; tk1 = tp[1]; tk2 = tp[2];
        const float* kp = projp + (size_t)rr * PPW + 192 + h * 36;
        float4 p0 = *(const float4*)kp;
        float4 p1 = *(const float4*)(kp + 4);
        float4 p2 = *(const float4*)(kp + 8);
        float xs[4] = {p0.x, p0.w, p1.z, p2.y};
        float ys[4] = {p0.y, p1.x, p1.w, p2.z};
        float zs[4] = {p0.z, p1.y, p2.x, p2.w};
        #pragma unroll
        for (int p = 0; p < 4; ++p) {
            kp_s[tid][p*3+0] = Rk[0]*xs[p] + Rk[1]*ys[p] + Rk[2]*zs[p] + tk0;
            kp_s[tid][p*3+1] = Rk[3]*xs[p] + Rk[4]*ys[p] + Rk[5]*zs[p] + tk1;
            kp_s[tid][p*3+2] = Rk[6]*xs[p] + Rk[7]*ys[p] + Rk[8]*zs[p] + tk2;
        }
    } else {
        int j = tid - 128;
        {
            int q = j >> 2, p = j & 3;
            const float* Rp = rots + (size_t)(rowq0 + q) * 9;
            const float* tp = trans + (size_t)(rowq0 + q) * 3;
            const float* qp = projp + (size_t)(rowq0 + q) * PPW + h * 12 + p * 3;
            float x = qp[0], y = qp[1], zc = qp[2];
            qp_s[q][p*3+0] = Rp[0]*x + Rp[1]*y + Rp[2]*zc + tp[0];
            qp_s[q][p*3+1] = Rp[3]*x + Rp[4]*y + Rp[5]*zc + tp[1];
            qp_s[q][p*3+2] = Rp[6]*x + Rp[7]*y + Rp[8]*zc + tp[2];
        }
        {
            const bf16_t* pK = projb + (size_t)rows_s[j] * PBW + OFFK + h * 64;
            #pragma unroll
            for (int u = 0; u < 8; ++u)
                *(bf16x8*)&Ks[j][u * 8] = *(const bf16x8*)(pK + u * 8);
        }
    }
    __syncthreads();
    // ---- Phase B: QK^T MFMA
    {
        #pragma unroll
        for (int j = 0; j < 4; ++j) {
            int T = w * 4 + j;
            int m = T & 1, n = T >> 1;
            f32x4 acc = (f32x4){0.f,0.f,0.f,0.f};
            #pragma unroll
            for (int kc = 0; kc < 2; ++kc) {
                bf16x8 a = *(const bf16x8*)&Qs[m*16 + (lane & 15)][kc*32 + (lane >> 4) * 8];
                bf16x8 b = *(const bf16x8*)&Ks[n*16 + (lane & 15)][kc*32 + (lane >> 4) * 8];
                acc = __builtin_amdgcn_mfma_f32_16x16x32_bf16(a, b, acc, 0, 0, 0);
            }
            #pragma unroll
            for (int i = 0; i < 4; ++i)
                att[m*16 + (lane >> 4)*4 + i][n*16 + (lane & 15)] = acc[i];
        }
    }
    __syncthreads();
    // ---- Phase C: stage V^T (tid>=128) + v-points rot->Vt (tid<128) + logit assembly
    if (tid < 128) {
        const float* vp = projp + (size_t)rows_s[tid] * PPW + 192 + h * 36 + 12;
        float4 a0 = *(const float4*)(vp);
        float4 a1 = *(const float4*)(vp + 4);
        float4 a2 = *(const float4*)(vp + 8);
        float4 a3 = *(const float4*)(vp + 12);
        float4 a4 = *(const float4*)(vp + 16);
        float4 a5 = *(const float4*)(vp + 20);
        float xs[8] = {a0.x, a0.w, a1.z, a2.y, a3.x, a3.w, a4.z, a5.y};
        float ys[8] = {a0.y, a1.x, a1.w, a2.z, a3.y, a4.x, a4.w, a5.z};
        float zs[8] = {a0.z, a1.y, a2.x, a2.w, a3.z, a4.y, a5.x, a5.w};
        #pragma unroll
        for (int p = 0; p < 8; ++p) {
            Vt[64 + p*3 + 0][tid] = (bf16_t)(Rk[0]*xs[p] + Rk[1]*ys[p] + Rk[2]*zs[p] + tk0);
            Vt[64 + p*3 + 1][tid] = (bf16_t)(Rk[3]*xs[p] + Rk[4]*ys[p] + Rk[5]*zs[p] + tk1);
            Vt[64 + p*3 + 2][tid] = (bf16_t)(Rk[6]*xs[p] + Rk[7]*ys[p] + Rk[8]*zs[p] + tk2);
        }
        {
            bf16x8 zz = {};
            *(bf16x8*)&Vt[88 + (tid & 7)][(tid >> 3) * 8] = zz;
        }
    } else {
        int krow = tid - 128;
        const bf16_t* p = projb + (size_t)rows_s[krow] * PBW + OFFV + h * 64;
        #pragma unroll
        for (int u4 = 0; u4 < 8; ++u4) {
            bf16x8 v = *(const bf16x8*)(p + u4 * 8);
            #pragma unroll
            for (int jj = 0; jj < 8; ++jj) Vt[u4 * 8 + jj][krow] = v[jj];
        }
    }
    {
        int q = tid >> 3, kg = tid & 7;
        float qp[12];
        #pragma unroll
        for (int e = 0; e < 12; ++e) qp[e] = qp_s[q][e];
        float qm = qm_s[q];
        const float* bT = biasT + ((size_t)(rowq0 + q) * 16 + h) * 128;
        #pragma unroll
        for (int j2 = 0; j2 < 16; ++j2) {
            int k = kg + j2 * 8;
            float4 k0 = *(const float4*)&kp_s[k][0];
            float4 k1 = *(const float4*)&kp_s[k][4];
            float4 k2 = *(const float4*)&kp_s[k][8];
            float d0 = qp[0]-k0.x, d1 = qp[1]-k0.y, d2_ = qp[2]-k0.z, d3 = qp[3]-k0.w;
            float d4 = qp[4]-k1.x, d5 = qp[5]-k1.y, d6 = qp[6]-k1.z, d7 = qp[7]-k1.w;
            float d8 = qp[8]-k2.x, d9 = qp[9]-k2.y, d10 = qp[10]-k2.z, d11 = qp[11]-k2.w;
            float dd = d0*d0+d1*d1+d2_*d2_+d3*d3+d4*d4+d5*d5+d6*d6+d7*d7+d8*d8+d9*d9+d10*d10+d11*d11;
            float val = att[q][k] * 0.07216878364870323f
                      + 0.5773502691896258f * bT[k]
                      + 100000.0f * (qm * km_s[k] - 1.0f)
                      - 0.5f * hw * dd;
            att[q][k] = val;
        }
    }
    __syncthreads();
    // ---- Phase D: softmax; then (after barrier, att dead) write P into overlaid Ps region + global
    {
        int q = tid >> 3, kg = tid & 7;
        float l[16];
        #pragma unroll
        for (int j2 = 0; j2 < 16; ++j2) l[j2] = att[q][kg + j2 * 8];
        float mx = l[0];
        #pragma unroll
        for (int j2 = 1; j2 < 16; ++j2) mx = fmaxf(mx, l[j2]);
        mx = fmaxf(mx, __shfl_xor(mx, 1));
        mx = fmaxf(mx, __shfl_xor(mx, 2));
        mx = fmaxf(mx, __shfl_xor(mx, 4));
        float se = 0.f;
        #pragma unroll
        for (int j2 = 0; j2 < 16; ++j2) { l[j2] = __expf(l[j2] - mx); se += l[j2]; }
        se += __shfl_xor(se, 1);
        se += __shfl_xor(se, 2);
        se += __shfl_xor(se, 4);
        float inv = 1.0f / se;
        __syncthreads();   // all att reads complete before Ps (same bytes) is written
        bf16_t* pg = Pbf + ((size_t)(rowq0 + q) * 16 + h) * 128;
        #pragma unroll
        for (int j2 = 0; j2 < 16; ++j2) {
            bf16_t pb = (bf16_t)(l[j2] * inv);
            Ps[q][kg + j2 * 8] = pb;
            pg[kg + j2 * 8] = pb;
        }
    }
    __syncthreads();
    // ---- Phase E: PV MFMA
    {
        #pragma unroll
        for (int j = 0; j < 3; ++j) {
            int T = w * 3 + j;
            int m = T & 1, n = T >> 1;
            f32x4 acc = (f32x4){0.f,0.f,0.f,0.f};
            #pragma unroll
            for (int kc = 0; kc < 4; ++kc) {
                bf16x8 a = *(const bf16x8*)&Ps[m*16 + (lane & 15)][kc*32 + (lane >> 4) * 8];
                bf16x8 b = *(const bf16x8*)&Vt[n*16 + (lane & 15)][kc*32 + (lane >> 4) * 8];
                acc = __builtin_amdgcn_mfma_f32_16x16x32_bf16(a, b, acc, 0, 0, 0);
            }
            int rowb = m * 16 + (lane >> 4) * 4;
            int col = lane & 15;
            if (n < 4) {
                #pragma unroll
                for (int i = 0; i < 4; ++i)
                    catb[(size_t)(rowq0 + rowb + i) * CATW + h * 64 + n * 16 + col] = (bf16_t)acc[i];
            } else {
                #pragma unroll
                for (int i = 0; i < 4; ++i)
                    optmp[rowb + i][(n - 4) * 16 + col] = acc[i];
            }
        }
    }
    __syncthreads();
    // ---- Phase F: o_pt inverse transform + norm
    {
        int q = tid >> 3, pp = tid & 7;
        float sx = optmp[q][pp * 3 + 0];
        float sy = optmp[q][pp * 3 + 1];
        float sz = optmp[q][pp * 3 + 2];
        const float* R = rots + (size_t)(rowq0 + q) * 9;
        const float* t = trans + (size_t)(rowq0 + q) * 3;
        float x = sx - t[0], y = sy - t[1], z2 = sz - t[2];
        float ox = R[0] * x + R[3] * y + R[6] * z2;
        float oy = R[1] * x + R[4] * y + R[7] * z2;
        float oz = R[2] * x + R[5] * y + R[8] * z2;
        bf16_t* cp = catb + (size_t)(rowq0 + q) * CATW;
        cp[1024 + h * 24 + pp * 3 + 0] = (bf16_t)ox;
        cp[1024 + h * 24 + pp * 3 + 1] = (bf16_t)oy;
        cp[1024 + h * 24 + pp * 3 + 2] = (bf16_t)oz;
        cp[1408 + h * 8 + pp] = (bf16_t)sqrtf(ox * ox + oy * oy + oz * oz + 1e-8f);
    }
}

// ---------------------------------------------------------------- o_pair: per rowq MFMA [16h x 128k] x [128k x 32c]
__global__ __launch_bounds__(256) void k_opair(const bf16_t* __restrict__ Pbf,
    const bf16_t* __restrict__ pzT, bf16_t* __restrict__ catb)
{
    int tid = threadIdx.x, lane = tid & 63, w = tid >> 6;
    size_t rowq = (size_t)blockIdx.x * 4 + w;
    const bf16_t* Pp = Pbf + rowq * 2048;
    const bf16_t* zp = pzT + rowq * 4096;
    bf16x8 pa[4];
    #pragma unroll
    for (int kc = 0; kc < 4; ++kc)
        pa[kc] = *(const bf16x8*)(Pp + (size_t)(lane & 15) * 128 + kc * 32 + (lane >> 4) * 8);
    #pragma unroll
    for (int ct = 0; ct < 2; ++ct) {
        f32x4 acc = (f32x4){0.f,0.f,0.f,0.f};
        #pragma unroll
        for (int kc = 0; kc < 4; ++kc) {
            bf16x8 b = *(const bf16x8*)(zp + (size_t)(ct * 16 + (lane & 15)) * 128 + kc * 32 + (lane >> 4) * 8);
            acc = __builtin_amdgcn_mfma_f32_16x16x32_bf16(pa[kc], b, acc, 0, 0, 0);
        }
        #pragma unroll
        for (int i = 0; i < 4; ++i) {
            int hh = (lane >> 4) * 4 + i;
            catb[rowq * CATW + 1536 + hh * 32 + ct * 16 + (lane & 15)] = (bf16_t)acc[i];
        }
    }
}

// ---------------------------------------------------------------- out GEMM, 64x128 tile (256 wgs), gld16 staging
__global__ __launch_bounds__(256) void gemm_out(const bf16_t* __restrict__ A, const bf16_t* __restrict__ BT,
    float* __restrict__ C)
{
    __shared__ bf16_t Asl[64][32];
    __shared__ bf16_t Bsl[128][32];
    const int tid = threadIdx.x, lane = tid & 63, w = tid >> 6;
    const int row0 = blockIdx.y * 64, col0 = blockIdx.x * 128;
    const int wr = (w >> 1) * 32, wc = (w & 1) * 64;
    const int K = 2048;
    const int sr = lane >> 2, k8 = (lane & 3) * 8;
    const bf16_t* Ab = A + (size_t)(row0 + w * 16 + sr) * K + k8;
    const bf16_t* Bb = BT + (size_t)(col0 + w * 32 + sr) * K + k8;
    f32x4 acc[2][4];
    #pragma unroll
    for (int m = 0; m < 2; ++m)
        #pragma unroll
        for (int n = 0; n < 4; ++n) acc[m][n] = (f32x4){0.f,0.f,0.f,0.f};
    for (int k0 = 0; k0 < K; k0 += 32) {
        __syncthreads();
        gld16(Ab + k0,          &Asl[w * 16][0]);
        gld16(Bb + k0,          &Bsl[w * 32][0]);
        gld16(Bb + k0 + 16 * K, &Bsl[w * 32 + 16][0]);
        __syncthreads();
        bf16x8 af[2], bfr[4];
        #pragma unroll
        for (int m = 0; m < 2; ++m) af[m]  = *(const bf16x8*)&Asl[wr + m*16 + (lane & 15)][(lane >> 4) * 8];
        #pragma unroll
        for (int n = 0; n < 4; ++n) bfr[n] = *(const bf16x8*)&Bsl[wc + n*16 + (lane & 15)][(lane >> 4) * 8];
        #pragma unroll
        for (int m = 0; m < 2; ++m)
            #pragma unroll
            for (int n = 0; n < 4; ++n)
                acc[m][n] = __builtin_amdgcn_mfma_f32_16x16x32_bf16(af[m], bfr[n], acc[m][n], 0, 0, 0);
    }
    #pragma unroll
    for (int m = 0; m < 2; ++m)
        #pragma unroll
        for (int n = 0; n < 4; ++n)
            #pragma unroll
            for (int i = 0; i < 4; ++i)
                C[(size_t)(row0 + wr + m*16 + (lane >> 4)*4 + i) * 512 + col0 + wc + n*16 + (lane & 15)] = acc[m][n][i];
}

// ---------------------------------------------------------------- launcher
extern "C" void kernel_launch(void* const* d_in, const int* in_sizes, int n_in,
                              void* d_out, int out_size, void* d_ws, size_t ws_size,
                              hipStream_t stream)
{
    (void)in_sizes; (void)n_in; (void)out_size;
    const float* s     = (const float*)d_in[0];
    const float* z     = (const float*)d_in[1];
    const float* trans = (const float*)d_in[2];
    const float* rots  = (const float*)d_in[3];
    const float* smask = (const float*)d_in[4];
    const int*   kidx  = (const int*)d_in[5];
    const float* Wq    = (const float*)d_in[6];
    const float* Wk    = (const float*)d_in[7];
    const float* Wv    = (const float*)d_in[8];
    const float* Wqp   = (const float*)d_in[9];
    const float* Wkvp  = (const float*)d_in[10];
    const float* Wb    = (const float*)d_in[11];
    const float* Wdz   = (const float*)d_in[12];
    const float* hw    = (const float*)d_in[13];
    const float* Wout  = (const float*)d_in[14];
    const float* g_s   = (const float*)d_in[15];
    const float* b_s   = (const float*)d_in[16];
    const float* g_z   = (const float*)d_in[17];
    const float* b_z   = (const float*)d_in[18];

    char* ws = (char*)d_ws;
    bf16_t* projb = (bf16_t*)(ws);                      // 25,165,824
    float*  projp = (float*)(ws + 25165824);            // 12,582,912
    float*  biasT = (float*)(ws + 37748736);            // 33,554,432
    bf16_t* wcatT = (bf16_t*)(ws + 71303168);           //  3,932,160
    bf16_t* s_nb  = (bf16_t*)(ws + 75235328);           //  4,194,304
    bf16_t* pzT   = (bf16_t*)(ws + 79429632);           // 33,554,432
    bf16_t* Pbf   = (bf16_t*)(ws + 112984064);          // 16,777,216
    bf16_t* catb  = (bf16_t*)(ws + 129761280);          // 16,777,216
    bf16_t* WoutT = (bf16_t*)(ws + 146538496);          //  2,097,152
    bf16_t* WzT   = (bf16_t*)(ws + 148635648);          //     12,288
    float*  Kv    = (float*)(ws + 148647936);           //        192
    if (ws_size < (size_t)148648128) return;
    float* out = (float*)d_out;

    k_prep<<<1761, 256, 0, stream>>>(Wq, Wk, Wv, Wqp, Wkvp, Wout, Wb, Wdz, g_z, b_z,
                                     s, g_s, b_s, wcatT, WoutT, WzT, Kv, s_nb);
    k_fused<<<3008, 256, 0, stream>>>(s_nb, wcatT, projb, projp, z, WzT, Kv, biasT, pzT);
    k_attn4<<<2048, 256, 0, stream>>>(projb, projp, biasT, rots, trans, smask, kidx, hw, catb, Pbf);
    k_opair<<<1024, 256, 0, stream>>>(Pbf, pzT, catb);
    gemm_out<<<dim3(4, 64), 256, 0, stream>>>(catb, WoutT, out);
}

// Round 12
// 206.698 us; speedup vs baseline: 1.0767x; 1.0191x over previous
//
#include <hip/hip_runtime.h>
#include <math.h>

#define D_N 4096
#define PBW 3072
#define PPW 768
#define OFFK 1024
#define OFFV 2048
#define CATW 2048

typedef __bf16 bf16_t;
typedef __bf16 bf16x8 __attribute__((ext_vector_type(8)));
typedef __bf16 bf16x4 __attribute__((ext_vector_type(4)));
typedef float f32x4 __attribute__((ext_vector_type(4)));

__device__ __forceinline__ void gld16(const void* g, void* l) {
    __builtin_amdgcn_global_load_lds((const __attribute__((address_space(1))) unsigned int*)g,
                                     (__attribute__((address_space(3))) unsigned int*)l, 16, 0, 0);
}

// ---------------------------------------------------------------- merged prep:
// blocks [0,480): wcatT ; [480,736): WoutT ; 736: WzT+Kv ; [737,1761): ln_s
__global__ __launch_bounds__(256) void k_prep(
    const float* __restrict__ Wq, const float* __restrict__ Wk, const float* __restrict__ Wv,
    const float* __restrict__ Wqp, const float* __restrict__ Wkvp, const float* __restrict__ Wout,
    const float* __restrict__ Wb, const float* __restrict__ Wdz,
    const float* __restrict__ gz, const float* __restrict__ bz,
    const float* __restrict__ s, const float* __restrict__ g_s, const float* __restrict__ b_s,
    bf16_t* __restrict__ wcatT, bf16_t* __restrict__ WoutT,
    bf16_t* __restrict__ WzT, float* __restrict__ Kv, bf16_t* __restrict__ s_nb)
{
    __shared__ float T[64][65];
    const int bx = blockIdx.x;
    const int tid = threadIdx.x;
    if (bx < 736) {
        const float* src; int ld, coff, r0;
        bf16_t* dst; int Rdst;
        if (bx < 480) {
            int c0 = (bx % 60) * 64;
            r0 = (bx / 60) * 64;
            if (c0 < 1024)      { src = Wq;   ld = 1024; coff = c0; }
            else if (c0 < 2048) { src = Wk;   ld = 1024; coff = c0 - 1024; }
            else if (c0 < 3072) { src = Wv;   ld = 1024; coff = c0 - 2048; }
            else if (c0 < 3264) { src = Wqp;  ld = 192;  coff = c0 - 3072; }
            else                { src = Wkvp; ld = 576;  coff = c0 - 3264; }
            dst = wcatT + (size_t)c0 * 512; Rdst = 512;
        } else {
            int b = bx - 480;
            int c0 = (b & 7) * 64;
            r0 = (b >> 3) * 64;
            src = Wout; ld = 512; coff = c0;
            dst = WoutT + (size_t)c0 * 2048; Rdst = 2048;
        }
        {
            int rr = tid >> 2, cb = (tid & 3) * 16;
            const float* p = src + (size_t)(r0 + rr) * ld + coff + cb;
            #pragma unroll
            for (int i = 0; i < 4; ++i)
                *(float4*)&T[rr][cb + i * 4] = *(const float4*)(p + i * 4);
        }
        __syncthreads();
        {
            int cc = tid >> 2, rb = (tid & 3) * 16;
            bf16_t* o = dst + (size_t)cc * Rdst + r0 + rb;
            bf16x8 o0, o1;
            #pragma unroll
            for (int j = 0; j < 8; ++j) o0[j] = (bf16_t)T[rb + j][cc];
            #pragma unroll
            for (int j = 0; j < 8; ++j) o1[j] = (bf16_t)T[rb + 8 + j][cc];
            *(bf16x8*)(o) = o0;
            *(bf16x8*)(o + 8) = o1;
        }
    } else if (bx == 736) {
        for (int i = tid; i < 6144; i += 256) {
            int j = i >> 7, c = i & 127;
            float w = (j < 16) ? Wb[c * 16 + j] : Wdz[c * 32 + (j - 16)];
            WzT[i] = (bf16_t)(gz[c] * w);
        }
        if (tid < 48) {
            int j = tid;
            float acc = 0.f;
            for (int c = 0; c < 128; ++c) {
                float w = (j < 16) ? Wb[c * 16 + j] : Wdz[c * 32 + (j - 16)];
                acc += bz[c] * w;
            }
            Kv[j] = acc;
        }
    } else {
        int row = (bx - 737) * 4 + (tid >> 6);
        int lane = tid & 63;
        const float4* p = (const float4*)(s + (size_t)row * 512);
        float4 v0 = p[lane];
        float4 v1 = p[lane + 64];
        float sum = v0.x + v0.y + v0.z + v0.w + v1.x + v1.y + v1.z + v1.w;
        float sq  = v0.x*v0.x + v0.y*v0.y + v0.z*v0.z + v0.w*v0.w
                  + v1.x*v1.x + v1.y*v1.y + v1.z*v1.z + v1.w*v1.w;
        #pragma unroll
        for (int off = 1; off < 64; off <<= 1) {
            sum += __shfl_xor(sum, off);
            sq  += __shfl_xor(sq, off);
        }
        float m = sum * (1.0f / 512.0f);
        float var = sq * (1.0f / 512.0f) - m * m;
        float rs = rsqrtf(var + 1e-5f);
        int c = lane * 4;
        int c2 = 256 + lane * 4;
        bf16x4 r0, r1;
        r0[0] = (bf16_t)((v0.x - m) * rs * g_s[c+0] + b_s[c+0]);
        r0[1] = (bf16_t)((v0.y - m) * rs * g_s[c+1] + b_s[c+1]);
        r0[2] = (bf16_t)((v0.z - m) * rs * g_s[c+2] + b_s[c+2]);
        r0[3] = (bf16_t)((v0.w - m) * rs * g_s[c+3] + b_s[c+3]);
        r1[0] = (bf16_t)((v1.x - m) * rs * g_s[c2+0] + b_s[c2+0]);
        r1[1] = (bf16_t)((v1.y - m) * rs * g_s[c2+1] + b_s[c2+1]);
        r1[2] = (bf16_t)((v1.z - m) * rs * g_s[c2+2] + b_s[c2+2]);
        r1[3] = (bf16_t)((v1.w - m) * rs * g_s[c2+3] + b_s[c2+3]);
        *(bf16x4*)(s_nb + (size_t)row * 512 + c)  = r0;
        *(bf16x4*)(s_nb + (size_t)row * 512 + c2) = r1;
    }
}

// ---------------------------------------------------------------- fused: proj GEMM (960 blocks, 16KB LDS) +
// z LN/proj (2048 blocks, REGISTER-resident, zero LDS, no manual waitcnt)
__global__ __launch_bounds__(256) void k_fused(
    const bf16_t* __restrict__ A, const bf16_t* __restrict__ BT,
    bf16_t* __restrict__ projb, float* __restrict__ projp,
    const float* __restrict__ z, const bf16_t* __restrict__ WzT, const float* __restrict__ Kv,
    float* __restrict__ biasT, bf16_t* __restrict__ pzT)
{
    __shared__ bf16_t Asl[128][32];
    __shared__ bf16_t Bsl[128][32];
    const int bx = blockIdx.x;
    const int tid = threadIdx.x, lane = tid & 63, w = tid >> 6;
    int gemm_id = -1, zid = 0;
    if (bx < 2880) {
        int s3 = bx % 3, b3 = bx / 3;
        if (s3 == 0) gemm_id = b3;
        else         zid = b3 * 2 + s3 - 1;
    } else {
        zid = 1920 + (bx - 2880);
    }

    if (gemm_id >= 0) {
        const int row0 = (gemm_id / 30) * 128, col0 = (gemm_id % 30) * 128;
        const int wr = (w >> 1) * 64, wc = (w & 1) * 64;
        const int K = 512;
        const int sr = lane >> 2, k8 = (lane & 3) * 8;
        const bf16_t* Ab = A + (size_t)(row0 + w * 32 + sr) * K + k8;
        const bf16_t* Bb = BT + (size_t)(col0 + w * 32 + sr) * K + k8;
        f32x4 acc[4][4];
        #pragma unroll
        for (int m = 0; m < 4; ++m)
            #pragma unroll
            for (int n = 0; n < 4; ++n) acc[m][n] = (f32x4){0.f,0.f,0.f,0.f};
        for (int k0 = 0; k0 < K; k0 += 32) {
            __syncthreads();
            gld16(Ab + k0,          &Asl[w * 32][0]);
            gld16(Ab + k0 + 16 * K, &Asl[w * 32 + 16][0]);
            gld16(Bb + k0,          &Bsl[w * 32][0]);
            gld16(Bb + k0 + 16 * K, &Bsl[w * 32 + 16][0]);
            __syncthreads();
            bf16x8 af[4], bfr[4];
            #pragma unroll
            for (int m = 0; m < 4; ++m) af[m]  = *(const bf16x8*)&Asl[wr + m*16 + (lane & 15)][(lane >> 4) * 8];
            #pragma unroll
            for (int n = 0; n < 4; ++n) bfr[n] = *(const bf16x8*)&Bsl[wc + n*16 + (lane & 15)][(lane >> 4) * 8];
            #pragma unroll
            for (int m = 0; m < 4; ++m)
                #pragma unroll
                for (int n = 0; n < 4; ++n)
                    acc[m][n] = __builtin_amdgcn_mfma_f32_16x16x32_bf16(af[m], bfr[n], acc[m][n], 0, 0, 0);
        }
        if (col0 < 3072) {
            #pragma unroll
            for (int m = 0; m < 4; ++m)
                #pragma unroll
                for (int n = 0; n < 4; ++n)
                    #pragma unroll
                    for (int i = 0; i < 4; ++i)
                        projb[(size_t)(row0 + wr + m*16 + (lane >> 4)*4 + i) * PBW + col0 + wc + n*16 + (lane & 15)]
                            = (bf16_t)acc[m][n][i];
        } else {
            #pragma unroll
            for (int m = 0; m < 4; ++m)
                #pragma unroll
                for (int n = 0; n < 4; ++n)
                    #pragma unroll
                    for (int i = 0; i < 4; ++i)
                        projp[(size_t)(row0 + wr + m*16 + (lane >> 4)*4 + i) * PPW + col0 - 3072 + wc + n*16 + (lane & 15)]
                            = acc[m][n][i];
        }
        return;
    }

    // ---------------- z LN + projection branch: register-resident, compiler-managed waits
    const int r16 = lane & 15, kg = lane >> 4;
    bf16x8 bfz[3][4];
    #pragma unroll
    for (int nt = 0; nt < 3; ++nt)
        #pragma unroll
        for (int kc = 0; kc < 4; ++kc)
            bfz[nt][kc] = *(const bf16x8*)(WzT + (size_t)(nt * 16 + r16) * 128 + kc * 32 + kg * 8);
    const float K0 = Kv[r16], K1 = Kv[16 + r16], K2 = Kv[32 + r16];
    const int gid = zid * 4 + w;

    #pragma unroll 2
    for (int it = 0; it < 4; ++it) {
        const int t_ = gid * 4 + it;
        const float* zp = z + ((size_t)t_ * 16 + r16) * 128 + kg * 8;
        float4 za[4], zc[4];
        float sum = 0.f, sq = 0.f;
        #pragma unroll
        for (int kc = 0; kc < 4; ++kc) {
            za[kc] = *(const float4*)(zp + kc * 32);
            zc[kc] = *(const float4*)(zp + kc * 32 + 4);
            sum += za[kc].x + za[kc].y + za[kc].z + za[kc].w + zc[kc].x + zc[kc].y + zc[kc].z + zc[kc].w;
            sq  += za[kc].x*za[kc].x + za[kc].y*za[kc].y + za[kc].z*za[kc].z + za[kc].w*za[kc].w
                 + zc[kc].x*zc[kc].x + zc[kc].y*zc[kc].y + zc[kc].z*zc[kc].z + zc[kc].w*zc[kc].w;
        }
        sum += __shfl_xor(sum, 16); sq += __shfl_xor(sq, 16);
        sum += __shfl_xor(sum, 32); sq += __shfl_xor(sq, 32);
        float m_ = sum * (1.0f / 128.0f);
        float rs_ = rsqrtf(sq * (1.0f / 128.0f) - m_ * m_ + 1e-5f);
        bf16x8 af[4];
        #pragma unroll
        for (int kc = 0; kc < 4; ++kc) {
            af[kc][0] = (bf16_t)((za[kc].x - m_) * rs_);
            af[kc][1] = (bf16_t)((za[kc].y - m_) * rs_);
            af[kc][2] = (bf16_t)((za[kc].z - m_) * rs_);
            af[kc][3] = (bf16_t)((za[kc].w - m_) * rs_);
            af[kc][4] = (bf16_t)((zc[kc].x - m_) * rs_);
            af[kc][5] = (bf16_t)((zc[kc].y - m_) * rs_);
            af[kc][6] = (bf16_t)((zc[kc].z - m_) * rs_);
            af[kc][7] = (bf16_t)((zc[kc].w - m_) * rs_);
        }
        f32x4 acc0 = (f32x4){0.f,0.f,0.f,0.f};
        f32x4 acc1 = (f32x4){0.f,0.f,0.f,0.f};
        f32x4 acc2 = (f32x4){0.f,0.f,0.f,0.f};
        #pragma unroll
        for (int kc = 0; kc < 4; ++kc) {
            acc0 = __builtin_amdgcn_mfma_f32_16x16x32_bf16(af[kc], bfz[0][kc], acc0, 0, 0, 0);
            acc1 = __builtin_amdgcn_mfma_f32_16x16x32_bf16(af[kc], bfz[1][kc], acc1, 0, 0, 0);
            acc2 = __builtin_amdgcn_mfma_f32_16x16x32_bf16(af[kc], bfz[2][kc], acc2, 0, 0, 0);
        }
        const int rowq_ = t_ >> 3;
        const int k0_ = ((t_ & 7) << 4) + kg * 4;
        float4 bw = {acc0[0] + K0, acc0[1] + K0, acc0[2] + K0, acc0[3] + K0};
        *(float4*)&biasT[((size_t)rowq_ * 16 + r16) * 128 + k0_] = bw;
        bf16x4 p1, p2;
        #pragma unroll
        for (int i2 = 0; i2 < 4; ++i2) { p1[i2] = (bf16_t)(acc1[i2] + K1); p2[i2] = (bf16_t)(acc2[i2] + K2); }
        *(bf16x4*)&pzT[((size_t)rowq_ * 32 + r16) * 128 + k0_] = p1;
        *(bf16x4*)&pzT[((size_t)rowq_ * 32 + 16 + r16) * 128 + k0_] = p2;
    }
}

// ---------------------------------------------------------------- attention: one wg per (nblk, head), XCD-swizzled,
// on-the-fly point rotation; LDS pool overlays (51.8 KB, 3 wg/CU); async-stage split (V + bias prefetched in phase A)
__global__ __launch_bounds__(256, 3) void k_attn4(
    const bf16_t* __restrict__ projb, const float* __restrict__ projp,
    const float* __restrict__ biasT, const float* __restrict__ rots,
    const float* __restrict__ trans, const float* __restrict__ smask,
    const int* __restrict__ kidx, const float* __restrict__ hwraw,
    bf16_t* __restrict__ catb, bf16_t* __restrict__ Pbf)
{
    __shared__ __align__(16) char pool[51840];
    bf16_t (*Qs)[72]   = (bf16_t(*)[72])pool;
    bf16_t (*Ks)[72]   = (bf16_t(*)[72])(pool + 32 * 72 * 2);
    bf16_t (*Vt)[136]  = (bf16_t(*)[136])pool;
    float  (*att)[132] = (float(*)[132])(pool + 26112);
    bf16_t (*Ps)[136]  = (bf16_t(*)[136])(pool + 26112);
    float  (*optmp)[33]= (float(*)[33])(pool + 26112 + 8704);
    float  (*kp_s)[12] = (float(*)[12])(pool + 43008);
    float  (*qp_s)[12] = (float(*)[12])(pool + 49152);
    float*  km_s       = (float*)(pool + 50688);
    float*  qm_s       = (float*)(pool + 51200);
    int*    rows_s     = (int*)(pool + 51328);

    const int wgid = blockIdx.x;
    const int swz = (wgid & 7) * 256 + (wgid >> 3);
    const int h = swz >> 7;
    const int nblk = swz & 127;
    const int tid = threadIdx.x;
    const int lane = tid & 63;
    const int w = tid >> 6;
    const int rowq0 = nblk * 32;
    const float hw = log1pf(__expf(hwraw[h])) * 0.13608276348795434f;

    if (tid < 128) {
        int ki = kidx[nblk * 128 + tid];
        int valid = (ki >= 0 && ki < D_N);
        int rr = ki < 0 ? 0 : (ki > D_N - 1 ? D_N - 1 : ki);
        rows_s[tid] = rr;
        km_s[tid] = valid ? smask[rr] : 0.0f;
    } else if (tid < 160) {
        qm_s[tid - 128] = smask[rowq0 + tid - 128];
    }
    __syncthreads();
    // ---- Phase A: stage Q (all), k-points+rot (tid<128), qp-rot + K (tid>=128);
    //      prefetch V rows (tid>=128) and biasT row (all) into registers (consumed in phase C)
    {
        int q = tid >> 3, cg = (tid & 7) * 8;
        *(bf16x8*)&Qs[q][cg] = *(const bf16x8*)(projb + (size_t)(rowq0 + q) * PBW + h * 64 + cg);
    }
    float Rk[9], tk0 = 0.f, tk1 = 0.f, tk2 = 0.f;
    bf16x8 vreg[8];
    if (tid < 128) {
        int rr = rows_s[tid];
        const float* Rp = rots + (size_t)rr * 9;
        const float* tp = trans + (size_t)rr * 3;
        #pragma unroll
        for (int e = 0; e < 9; ++e) Rk[e] = Rp[e];
        tk0 = tp[0]; tk1 = tp[1]; tk2 = tp[2];
        const float* kp = projp + (size_t)rr * PPW + 192 + h * 36;
        float4 p0 = *(const float4*)kp;
        float4 p1 = *(const float4*)(kp + 4);
        float4 p2 = *(const float4*)(kp + 8);
        float xs[4] = {p0.x, p0.w, p1.z, p2.y};
        float ys[4] = {p0.y, p1.x, p1.w, p2.z};
        float zs[4] = {p0.z, p1.y, p2.x, p2.w};
        #pragma unroll
        for (int p = 0; p < 4; ++p) {
            kp_s[tid][p*3+0] = Rk[0]*xs[p] + Rk[1]*ys[p] + Rk[2]*zs[p] + tk0;
            kp_s[tid][p*3+1] = Rk[3]*xs[p] + Rk[4]*ys[p] + Rk[5]*zs[p] + tk1;
            kp_s[tid][p*3+2] = Rk[6]*xs[p] + Rk[7]*ys[p] + Rk[8]*zs[p] + tk2;
        }
    } else {
        int j = tid - 128;
        {
            int q = j >> 2, p = j & 3;
            const float* Rp = rots + (size_t)(rowq0 + q) * 9;
            const float* tp = trans + (size_t)(rowq0 + q) * 3;
            const float* qp = projp + (size_t)(rowq0 + q) * PPW + h * 12 + p * 3;
            float x = qp[0], y = qp[1], zc = qp[2];
            qp_s[q][p*3+0] = Rp[0]*x + Rp[1]*y + Rp[2]*zc + tp[0];
            qp_s[q][p*3+1] = Rp[3]*x + Rp[4]*y + Rp[5]*zc + tp[1];
            qp_s[q][p*3+2] = Rp[6]*x + Rp[7]*y + Rp[8]*zc + tp[2];
        }
        {
            const bf16_t* pK = projb + (size_t)rows_s[j] * PBW + OFFK + h * 64;
            #pragma unroll
            for (int u = 0; u < 8; ++u)
                *(bf16x8*)&Ks[j][u * 8] = *(const bf16x8*)(pK + u * 8);
        }
        {   // V prefetch (T14 async-stage: issue early, LDS-write late in phase C)
            const bf16_t* pV = projb + (size_t)rows_s[j] * PBW + OFFV + h * 64;
            #pragma unroll
            for (int u4 = 0; u4 < 8; ++u4)
                vreg[u4] = *(const bf16x8*)(pV + u4 * 8);
        }
    }
    float bT_reg[16];
    {
        int q = tid >> 3, kg = tid & 7;
        const float* bT = biasT + ((size_t)(rowq0 + q) * 16 + h) * 128 + kg;
        #pragma unroll
        for (int j2 = 0; j2 < 16; ++j2) bT_reg[j2] = bT[j2 * 8];
    }
    __syncthreads();
    // ---- Phase B: QK^T MFMA
    {
        #pragma unroll
        for (int j = 0; j < 4; ++j) {
            int T = w * 4 + j;
            int m = T & 1, n = T >> 1;
            f32x4 acc = (f32x4){0.f,0.f,0.f,0.f};
            #pragma unroll
            for (int kc = 0; kc < 2; ++kc) {
                bf16x8 a = *(const bf16x8*)&Qs[m*16 + (lane & 15)][kc*32 + (lane >> 4) * 8];
                bf16x8 b = *(const bf16x8*)&Ks[n*16 + (lane & 15)][kc*32 + (lane >> 4) * 8];
                acc = __builtin_amdgcn_mfma_f32_16x16x32_bf16(a, b, acc, 0, 0, 0);
            }
            #pragma unroll
            for (int i = 0; i < 4; ++i)
                att[m*16 + (lane >> 4)*4 + i][n*16 + (lane & 15)] = acc[i];
        }
    }
    __syncthreads();
    // ---- Phase C: write prefetched V^T (tid>=128) + v-points rot->Vt (tid<128) + logit assembly
    if (tid < 128) {
        const float* vp = projp + (size_t)rows_s[tid] * PPW + 192 + h * 36 + 12;
        float4 a0 = *(const float4*)(vp);
        float4 a1 = *(const float4*)(vp + 4);
        float4 a2 = *(const float4*)(vp + 8);
        float4 a3 = *(const float4*)(vp + 12);
        float4 a4 = *(const float4*)(vp + 16);
        float4 a5 = *(const float4*)(vp + 20);
        float xs[8] = {a0.x, a0.w, a1.z, a2.y, a3.x, a3.w, a4.z, a5.y};
        float ys[8] = {a0.y, a1.x, a1.w, a2.z, a3.y, a4.x, a4.w, a5.z};
        float zs[8] = {a0.z, a1.y, a2.x, a2.w, a3.z, a4.y, a5.x, a5.w};
        #pragma unroll
        for (int p = 0; p < 8; ++p) {
            Vt[64 + p*3 + 0][tid] = (bf16_t)(Rk[0]*xs[p] + Rk[1]*ys[p] + Rk[2]*zs[p] + tk0);
            Vt[64 + p*3 + 1][tid] = (bf16_t)(Rk[3]*xs[p] + Rk[4]*ys[p] + Rk[5]*zs[p] + tk1);
            Vt[64 + p*3 + 2][tid] = (bf16_t)(Rk[6]*xs[p] + Rk[7]*ys[p] + Rk[8]*zs[p] + tk2);
        }
        {
            bf16x8 zz = {};
            *(bf16x8*)&Vt[88 + (tid & 7)][(tid >> 3) * 8] = zz;
        }
    } else {
        int krow = tid - 128;
        #pragma unroll
        for (int u4 = 0; u4 < 8; ++u4) {
            #pragma unroll
            for (int jj = 0; jj < 8; ++jj) Vt[u4 * 8 + jj][krow] = vreg[u4][jj];
        }
    }
    {
        int q = tid >> 3, kg = tid & 7;
        float qp[12];
        #pragma unroll
        for (int e = 0; e < 12; ++e) qp[e] = qp_s[q][e];
        float qm = qm_s[q];
        #pragma unroll
        for (int j2 = 0; j2 < 16; ++j2) {
            int k = kg + j2 * 8;
            float4 k0 = *(const float4*)&kp_s[k][0];
            float4 k1 = *(const float4*)&kp_s[k][4];
            float4 k2 = *(const float4*)&kp_s[k][8];
            float d0 = qp[0]-k0.x, d1 = qp[1]-k0.y, d2_ = qp[2]-k0.z, d3 = qp[3]-k0.w;
            float d4 = qp[4]-k1.x, d5 = qp[5]-k1.y, d6 = qp[6]-k1.z, d7 = qp[7]-k1.w;
            float d8 = qp[8]-k2.x, d9 = qp[9]-k2.y, d10 = qp[10]-k2.z, d11 = qp[11]-k2.w;
            float dd = d0*d0+d1*d1+d2_*d2_+d3*d3+d4*d4+d5*d5+d6*d6+d7*d7+d8*d8+d9*d9+d10*d10+d11*d11;
            float val = att[q][k] * 0.07216878364870323f
                      + 0.5773502691896258f * bT_reg[j2]
                      + 100000.0f * (qm * km_s[k] - 1.0f)
                      - 0.5f * hw * dd;
            att[q][k] = val;
        }
    }
    __syncthreads();
    // ---- Phase D: softmax; then (after barrier, att dead) write P into overlaid Ps region + global
    {
        int q = tid >> 3, kg = tid & 7;
        float l[16];
        #pragma unroll
        for (int j2 = 0; j2 < 16; ++j2) l[j2] = att[q][kg + j2 * 8];
        float mx = l[0];
        #pragma unroll
        for (int j2 = 1; j2 < 16; ++j2) mx = fmaxf(mx, l[j2]);
        mx = fmaxf(mx, __shfl_xor(mx, 1));
        mx = fmaxf(mx, __shfl_xor(mx, 2));
        mx = fmaxf(mx, __shfl_xor(mx, 4));
        float se = 0.f;
        #pragma unroll
        for (int j2 = 0; j2 < 16; ++j2) { l[j2] = __expf(l[j2] - mx); se += l[j2]; }
        se += __shfl_xor(se, 1);
        se += __shfl_xor(se, 2);
        se += __shfl_xor(se, 4);
        float inv = 1.0f / se;
        __syncthreads();   // all att reads complete before Ps (same bytes) is written
        bf16_t* pg = Pbf + ((size_t)(rowq0 + q) * 16 + h) * 128;
        #pragma unroll
        for (int j2 = 0; j2 < 16; ++j2) {
            bf16_t pb = (bf16_t)(l[j2] * inv);
            Ps[q][kg + j2 * 8] = pb;
            pg[kg + j2 * 8] = pb;
        }
    }
    __syncthreads();
    // ---- Phase E: PV MFMA
    {
        #pragma unroll
        for (int j = 0; j < 3; ++j) {
            int T = w * 3 + j;
            int m = T & 1, n = T >> 1;
            f32x4 acc = (f32x4){0.f,0.f,0.f,0.f};
            #pragma unroll
            for (int kc = 0; kc < 4; ++kc) {
                bf16x8 a = *(const bf16x8*)&Ps[m*16 + (lane & 15)][kc*32 + (lane >> 4) * 8];
                bf16x8 b = *(const bf16x8*)&Vt[n*16 + (lane & 15)][kc*32 + (lane >> 4) * 8];
                acc = __builtin_amdgcn_mfma_f32_16x16x32_bf16(a, b, acc, 0, 0, 0);
            }
            int rowb = m * 16 + (lane >> 4) * 4;
            int col = lane & 15;
            if (n < 4) {
                #pragma unroll
                for (int i = 0; i < 4; ++i)
                    catb[(size_t)(rowq0 + rowb + i) * CATW + h * 64 + n * 16 + col] = (bf16_t)acc[i];
            } else {
                #pragma unroll
                for (int i = 0; i < 4; ++i)
                    optmp[rowb + i][(n - 4) * 16 + col] = acc[i];
            }
        }
    }
    __syncthreads();
    // ---- Phase F: o_pt inverse transform + norm
    {
        int q = tid >> 3, pp = tid & 7;
        float sx = optmp[q][pp * 3 + 0];
        float sy = optmp[q][pp * 3 + 1];
        float sz = optmp[q][pp * 3 + 2];
        const float* R = rots + (size_t)(rowq0 + q) * 9;
        const float* t = trans + (size_t)(rowq0 + q) * 3;
        float x = sx - t[0], y = sy - t[1], z2 = sz - t[2];
        float ox = R[0] * x + R[3] * y + R[6] * z2;
        float oy = R[1] * x + R[4] * y + R[7] * z2;
        float oz = R[2] * x + R[5] * y + R[8] * z2;
        bf16_t* cp = catb + (size_t)(rowq0 + q) * CATW;
        cp[1024 + h * 24 + pp * 3 + 0] = (bf16_t)ox;
        cp[1024 + h * 24 + pp * 3 + 1] = (bf16_t)oy;
        cp[1024 + h * 24 + pp * 3 + 2] = (bf16_t)oz;
        cp[1408 + h * 8 + pp] = (bf16_t)sqrtf(ox * ox + oy * oy + oz * oz + 1e-8f);
    }
}

// ---------------------------------------------------------------- o_pair: per rowq MFMA [16h x 128k] x [128k x 32c]
__global__ __launch_bounds__(256) void k_opair(const bf16_t* __restrict__ Pbf,
    const bf16_t* __restrict__ pzT, bf16_t* __restrict__ catb)
{
    int tid = threadIdx.x, lane = tid & 63, w = tid >> 6;
    size_t rowq = (size_t)blockIdx.x * 4 + w;
    const bf16_t* Pp = Pbf + rowq * 2048;
    const bf16_t* zp = pzT + rowq * 4096;
    bf16x8 pa[4];
    #pragma unroll
    for (int kc = 0; kc < 4; ++kc)
        pa[kc] = *(const bf16x8*)(Pp + (size_t)(lane & 15) * 128 + kc * 32 + (lane >> 4) * 8);
    #pragma unroll
    for (int ct = 0; ct < 2; ++ct) {
        f32x4 acc = (f32x4){0.f,0.f,0.f,0.f};
        #pragma unroll
        for (int kc = 0; kc < 4; ++kc) {
            bf16x8 b = *(const bf16x8*)(zp + (size_t)(ct * 16 + (lane & 15)) * 128 + kc * 32 + (lane >> 4) * 8);
            acc = __builtin_amdgcn_mfma_f32_16x16x32_bf16(pa[kc], b, acc, 0, 0, 0);
        }
        #pragma unroll
        for (int i = 0; i < 4; ++i) {
            int hh = (lane >> 4) * 4 + i;
            catb[rowq * CATW + 1536 + hh * 32 + ct * 16 + (lane & 15)] = (bf16_t)acc[i];
        }
    }
}

// ---------------------------------------------------------------- out GEMM, 64x128 tile, XCD-friendly flat id:
// by = id&63, bx = id>>6 -> the 4 col-blocks of a row-tile share id mod 8 (same XCD) -> A re-reads hit L2
__global__ __launch_bounds__(256) void gemm_out(const bf16_t* __restrict__ A, const bf16_t* __restrict__ BT,
    float* __restrict__ C)
{
    __shared__ bf16_t Asl[64][32];
    __shared__ bf16_t Bsl[128][32];
    const int tid = threadIdx.x, lane = tid & 63, w = tid >> 6;
    const int by = blockIdx.x & 63, bxc = blockIdx.x >> 6;
    const int row0 = by * 64, col0 = bxc * 128;
    const int wr = (w >> 1) * 32, wc = (w & 1) * 64;
    const int K = 2048;
    const int sr = lane >> 2, k8 = (lane & 3) * 8;
    const bf16_t* Ab = A + (size_t)(row0 + w * 16 + sr) * K + k8;
    const bf16_t* Bb = BT + (size_t)(col0 + w * 32 + sr) * K + k8;
    f32x4 acc[2][4];
    #pragma unroll
    for (int m = 0; m < 2; ++m)
        #pragma unroll
        for (int n = 0; n < 4; ++n) acc[m][n] = (f32x4){0.f,0.f,0.f,0.f};
    for (int k0 = 0; k0 < K; k0 += 32) {
        __syncthreads();
        gld16(Ab + k0,          &Asl[w * 16][0]);
        gld16(Bb + k0,          &Bsl[w * 32][0]);
        gld16(Bb + k0 + 16 * K, &Bsl[w * 32 + 16][0]);
        __syncthreads();
        bf16x8 af[2], bfr[4];
        #pragma unroll
        for (int m = 0; m < 2; ++m) af[m]  = *(const bf16x8*)&Asl[wr + m*16 + (lane & 15)][(lane >> 4) * 8];
        #pragma unroll
        for (int n = 0; n < 4; ++n) bfr[n] = *(const bf16x8*)&Bsl[wc + n*16 + (lane & 15)][(lane >> 4) * 8];
        #pragma unroll
        for (int m = 0; m < 2; ++m)
            #pragma unroll
            for (int n = 0; n < 4; ++n)
                acc[m][n] = __builtin_amdgcn_mfma_f32_16x16x32_bf16(af[m], bfr[n], acc[m][n], 0, 0, 0);
    }
    #pragma unroll
    for (int m = 0; m < 2; ++m)
        #pragma unroll
        for (int n = 0; n < 4; ++n)
            #pragma unroll
            for (int i = 0; i < 4; ++i)
                C[(size_t)(row0 + wr + m*16 + (lane >> 4)*4 + i) * 512 + col0 + wc + n*16 + (lane & 15)] = acc[m][n][i];
}

// ---------------------------------------------------------------- launcher
extern "C" void kernel_launch(void* const* d_in, const int* in_sizes, int n_in,
                              void* d_out, int out_size, void* d_ws, size_t ws_size,
                              hipStream_t stream)
{
    (void)in_sizes; (void)n_in; (void)out_size;
    const float* s     = (const float*)d_in[0];
    const float* z     = (const float*)d_in[1];
    const float* trans = (const float*)d_in[2];
    const float* rots  = (const float*)d_in[3];
    const float* smask = (const float*)d_in[4];
    const int*   kidx  = (const int*)d_in[5];
    const float* Wq    = (const float*)d_in[6];
    const float* Wk    = (const float*)d_in[7];
    const float* Wv    = (const float*)d_in[8];
    const float* Wqp   = (const float*)d_in[9];
    const float* Wkvp  = (const float*)d_in[10];
    const float* Wb    = (const float*)d_in[11];
    const float* Wdz   = (const float*)d_in[12];
    const float* hw    = (const float*)d_in[13];
    const float* Wout  = (const float*)d_in[14];
    const float* g_s   = (const float*)d_in[15];
    const float* b_s   = (const float*)d_in[16];
    const float* g_z   = (const float*)d_in[17];
    const float* b_z   = (const float*)d_in[18];

    char* ws = (char*)d_ws;
    bf16_t* projb = (bf16_t*)(ws);                      // 25,165,824
    float*  projp = (float*)(ws + 25165824);            // 12,582,912
    float*  biasT = (float*)(ws + 37748736);            // 33,554,432
    bf16_t* wcatT = (bf16_t*)(ws + 71303168);           //  3,932,160
    bf16_t* s_nb  = (bf16_t*)(ws + 75235328);           //  4,194,304
    bf16_t* pzT   = (bf16_t*)(ws + 79429632);           // 33,554,432
    bf16_t* Pbf   = (bf16_t*)(ws + 112984064);          // 16,777,216
    bf16_t* catb  = (bf16_t*)(ws + 129761280);          // 16,777,216
    bf16_t* WoutT = (bf16_t*)(ws + 146538496);          //  2,097,152
    bf16_t* WzT   = (bf16_t*)(ws + 148635648);          //     12,288
    float*  Kv    = (float*)(ws + 148647936);           //        192
    if (ws_size < (size_t)148648128) return;
    float* out = (float*)d_out;

    k_prep<<<1761, 256, 0, stream>>>(Wq, Wk, Wv, Wqp, Wkvp, Wout, Wb, Wdz, g_z, b_z,
                                     s, g_s, b_s, wcatT, WoutT, WzT, Kv, s_nb);
    k_fused<<<3008, 256, 0, stream>>>(s_nb, wcatT, projb, projp, z, WzT, Kv, biasT, pzT);
    k_attn4<<<2048, 256, 0, stream>>>(projb, projp, biasT, rots, trans, smask, kidx, hw, catb, Pbf);
    k_opair<<<1024, 256, 0, stream>>>(Pbf, pzT, catb);
    gemm_out<<<256, 256, 0, stream>>>(catb, WoutT, out);
}

// Round 13
// 206.552 us; speedup vs baseline: 1.0775x; 1.0007x over previous
//
#include <hip/hip_runtime.h>
#include <math.h>

#define D_N 4096
#define PBW 3072
#define PPW 768
#define OFFK 1024
#define OFFV 2048
#define CATW 2048

typedef __bf16 bf16_t;
typedef __bf16 bf16x8 __attribute__((ext_vector_type(8)));
typedef __bf16 bf16x4 __attribute__((ext_vector_type(4)));
typedef float f32x4 __attribute__((ext_vector_type(4)));

__device__ __forceinline__ void gld16(const void* g, void* l) {
    __builtin_amdgcn_global_load_lds((const __attribute__((address_space(1))) unsigned int*)g,
                                     (__attribute__((address_space(3))) unsigned int*)l, 16, 0, 0);
}

// ---------------------------------------------------------------- merged prep:
// blocks [0,480): wcatT ; [480,736): WoutT ; 736: WzT+Kv ; [737,1761): ln_s
__global__ __launch_bounds__(256) void k_prep(
    const float* __restrict__ Wq, const float* __restrict__ Wk, const float* __restrict__ Wv,
    const float* __restrict__ Wqp, const float* __restrict__ Wkvp, const float* __restrict__ Wout,
    const float* __restrict__ Wb, const float* __restrict__ Wdz,
    const float* __restrict__ gz, const float* __restrict__ bz,
    const float* __restrict__ s, const float* __restrict__ g_s, const float* __restrict__ b_s,
    bf16_t* __restrict__ wcatT, bf16_t* __restrict__ WoutT,
    bf16_t* __restrict__ WzT, float* __restrict__ Kv, bf16_t* __restrict__ s_nb)
{
    __shared__ float T[64][65];
    const int bx = blockIdx.x;
    const int tid = threadIdx.x;
    if (bx < 736) {
        const float* src; int ld, coff, r0;
        bf16_t* dst; int Rdst;
        if (bx < 480) {
            int c0 = (bx % 60) * 64;
            r0 = (bx / 60) * 64;
            if (c0 < 1024)      { src = Wq;   ld = 1024; coff = c0; }
            else if (c0 < 2048) { src = Wk;   ld = 1024; coff = c0 - 1024; }
            else if (c0 < 3072) { src = Wv;   ld = 1024; coff = c0 - 2048; }
            else if (c0 < 3264) { src = Wqp;  ld = 192;  coff = c0 - 3072; }
            else                { src = Wkvp; ld = 576;  coff = c0 - 3264; }
            dst = wcatT + (size_t)c0 * 512; Rdst = 512;
        } else {
            int b = bx - 480;
            int c0 = (b & 7) * 64;
            r0 = (b >> 3) * 64;
            src = Wout; ld = 512; coff = c0;
            dst = WoutT + (size_t)c0 * 2048; Rdst = 2048;
        }
        {
            int rr = tid >> 2, cb = (tid & 3) * 16;
            const float* p = src + (size_t)(r0 + rr) * ld + coff + cb;
            #pragma unroll
            for (int i = 0; i < 4; ++i)
                *(float4*)&T[rr][cb + i * 4] = *(const float4*)(p + i * 4);
        }
        __syncthreads();
        {
            int cc = tid >> 2, rb = (tid & 3) * 16;
            bf16_t* o = dst + (size_t)cc * Rdst + r0 + rb;
            bf16x8 o0, o1;
            #pragma unroll
            for (int j = 0; j < 8; ++j) o0[j] = (bf16_t)T[rb + j][cc];
            #pragma unroll
            for (int j = 0; j < 8; ++j) o1[j] = (bf16_t)T[rb + 8 + j][cc];
            *(bf16x8*)(o) = o0;
            *(bf16x8*)(o + 8) = o1;
        }
    } else if (bx == 736) {
        for (int i = tid; i < 6144; i += 256) {
            int j = i >> 7, c = i & 127;
            float w = (j < 16) ? Wb[c * 16 + j] : Wdz[c * 32 + (j - 16)];
            WzT[i] = (bf16_t)(gz[c] * w);
        }
        if (tid < 48) {
            int j = tid;
            float acc = 0.f;
            for (int c = 0; c < 128; ++c) {
                float w = (j < 16) ? Wb[c * 16 + j] : Wdz[c * 32 + (j - 16)];
                acc += bz[c] * w;
            }
            Kv[j] = acc;
        }
    } else {
        int row = (bx - 737) * 4 + (tid >> 6);
        int lane = tid & 63;
        const float4* p = (const float4*)(s + (size_t)row * 512);
        float4 v0 = p[lane];
        float4 v1 = p[lane + 64];
        float sum = v0.x + v0.y + v0.z + v0.w + v1.x + v1.y + v1.z + v1.w;
        float sq  = v0.x*v0.x + v0.y*v0.y + v0.z*v0.z + v0.w*v0.w
                  + v1.x*v1.x + v1.y*v1.y + v1.z*v1.z + v1.w*v1.w;
        #pragma unroll
        for (int off = 1; off < 64; off <<= 1) {
            sum += __shfl_xor(sum, off);
            sq  += __shfl_xor(sq, off);
        }
        float m = sum * (1.0f / 512.0f);
        float var = sq * (1.0f / 512.0f) - m * m;
        float rs = rsqrtf(var + 1e-5f);
        int c = lane * 4;
        int c2 = 256 + lane * 4;
        bf16x4 r0, r1;
        r0[0] = (bf16_t)((v0.x - m) * rs * g_s[c+0] + b_s[c+0]);
        r0[1] = (bf16_t)((v0.y - m) * rs * g_s[c+1] + b_s[c+1]);
        r0[2] = (bf16_t)((v0.z - m) * rs * g_s[c+2] + b_s[c+2]);
        r0[3] = (bf16_t)((v0.w - m) * rs * g_s[c+3] + b_s[c+3]);
        r1[0] = (bf16_t)((v1.x - m) * rs * g_s[c2+0] + b_s[c2+0]);
        r1[1] = (bf16_t)((v1.y - m) * rs * g_s[c2+1] + b_s[c2+1]);
        r1[2] = (bf16_t)((v1.z - m) * rs * g_s[c2+2] + b_s[c2+2]);
        r1[3] = (bf16_t)((v1.w - m) * rs * g_s[c2+3] + b_s[c2+3]);
        *(bf16x4*)(s_nb + (size_t)row * 512 + c)  = r0;
        *(bf16x4*)(s_nb + (size_t)row * 512 + c2) = r1;
    }
}

// ---------------------------------------------------------------- fused: proj GEMM (960 blocks, 16KB LDS) +
// z LN/proj (2048 blocks, REGISTER-resident, zero LDS, no manual waitcnt)
__global__ __launch_bounds__(256) void k_fused(
    const bf16_t* __restrict__ A, const bf16_t* __restrict__ BT,
    bf16_t* __restrict__ projb, float* __restrict__ projp,
    const float* __restrict__ z, const bf16_t* __restrict__ WzT, const float* __restrict__ Kv,
    float* __restrict__ biasT, bf16_t* __restrict__ pzT)
{
    __shared__ bf16_t Asl[128][32];
    __shared__ bf16_t Bsl[128][32];
    const int bx = blockIdx.x;
    const int tid = threadIdx.x, lane = tid & 63, w = tid >> 6;
    int gemm_id = -1, zid = 0;
    if (bx < 2880) {
        int s3 = bx % 3, b3 = bx / 3;
        if (s3 == 0) gemm_id = b3;
        else         zid = b3 * 2 + s3 - 1;
    } else {
        zid = 1920 + (bx - 2880);
    }

    if (gemm_id >= 0) {
        const int row0 = (gemm_id / 30) * 128, col0 = (gemm_id % 30) * 128;
        const int wr = (w >> 1) * 64, wc = (w & 1) * 64;
        const int K = 512;
        const int sr = lane >> 2, k8 = (lane & 3) * 8;
        const bf16_t* Ab = A + (size_t)(row0 + w * 32 + sr) * K + k8;
        const bf16_t* Bb = BT + (size_t)(col0 + w * 32 + sr) * K + k8;
        f32x4 acc[4][4];
        #pragma unroll
        for (int m = 0; m < 4; ++m)
            #pragma unroll
            for (int n = 0; n < 4; ++n) acc[m][n] = (f32x4){0.f,0.f,0.f,0.f};
        for (int k0 = 0; k0 < K; k0 += 32) {
            __syncthreads();
            gld16(Ab + k0,          &Asl[w * 32][0]);
            gld16(Ab + k0 + 16 * K, &Asl[w * 32 + 16][0]);
            gld16(Bb + k0,          &Bsl[w * 32][0]);
            gld16(Bb + k0 + 16 * K, &Bsl[w * 32 + 16][0]);
            __syncthreads();
            bf16x8 af[4], bfr[4];
            #pragma unroll
            for (int m = 0; m < 4; ++m) af[m]  = *(const bf16x8*)&Asl[wr + m*16 + (lane & 15)][(lane >> 4) * 8];
            #pragma unroll
            for (int n = 0; n < 4; ++n) bfr[n] = *(const bf16x8*)&Bsl[wc + n*16 + (lane & 15)][(lane >> 4) * 8];
            #pragma unroll
            for (int m = 0; m < 4; ++m)
                #pragma unroll
                for (int n = 0; n < 4; ++n)
                    acc[m][n] = __builtin_amdgcn_mfma_f32_16x16x32_bf16(af[m], bfr[n], acc[m][n], 0, 0, 0);
        }
        if (col0 < 3072) {
            #pragma unroll
            for (int m = 0; m < 4; ++m)
                #pragma unroll
                for (int n = 0; n < 4; ++n)
                    #pragma unroll
                    for (int i = 0; i < 4; ++i)
                        projb[(size_t)(row0 + wr + m*16 + (lane >> 4)*4 + i) * PBW + col0 + wc + n*16 + (lane & 15)]
                            = (bf16_t)acc[m][n][i];
        } else {
            #pragma unroll
            for (int m = 0; m < 4; ++m)
                #pragma unroll
                for (int n = 0; n < 4; ++n)
                    #pragma unroll
                    for (int i = 0; i < 4; ++i)
                        projp[(size_t)(row0 + wr + m*16 + (lane >> 4)*4 + i) * PPW + col0 - 3072 + wc + n*16 + (lane & 15)]
                            = acc[m][n][i];
        }
        return;
    }

    // ---------------- z LN + projection branch: register-resident, compiler-managed waits
    const int r16 = lane & 15, kg = lane >> 4;
    bf16x8 bfz[3][4];
    #pragma unroll
    for (int nt = 0; nt < 3; ++nt)
        #pragma unroll
        for (int kc = 0; kc < 4; ++kc)
            bfz[nt][kc] = *(const bf16x8*)(WzT + (size_t)(nt * 16 + r16) * 128 + kc * 32 + kg * 8);
    const float K0 = Kv[r16], K1 = Kv[16 + r16], K2 = Kv[32 + r16];
    const int gid = zid * 4 + w;

    #pragma unroll 2
    for (int it = 0; it < 4; ++it) {
        const int t_ = gid * 4 + it;
        const float* zp = z + ((size_t)t_ * 16 + r16) * 128 + kg * 8;
        float4 za[4], zc[4];
        float sum = 0.f, sq = 0.f;
        #pragma unroll
        for (int kc = 0; kc < 4; ++kc) {
            za[kc] = *(const float4*)(zp + kc * 32);
            zc[kc] = *(const float4*)(zp + kc * 32 + 4);
            sum += za[kc].x + za[kc].y + za[kc].z + za[kc].w + zc[kc].x + zc[kc].y + zc[kc].z + zc[kc].w;
            sq  += za[kc].x*za[kc].x + za[kc].y*za[kc].y + za[kc].z*za[kc].z + za[kc].w*za[kc].w
                 + zc[kc].x*zc[kc].x + zc[kc].y*zc[kc].y + zc[kc].z*zc[kc].z + zc[kc].w*zc[kc].w;
        }
        sum += __shfl_xor(sum, 16); sq += __shfl_xor(sq, 16);
        sum += __shfl_xor(sum, 32); sq += __shfl_xor(sq, 32);
        float m_ = sum * (1.0f / 128.0f);
        float rs_ = rsqrtf(sq * (1.0f / 128.0f) - m_ * m_ + 1e-5f);
        bf16x8 af[4];
        #pragma unroll
        for (int kc = 0; kc < 4; ++kc) {
            af[kc][0] = (bf16_t)((za[kc].x - m_) * rs_);
            af[kc][1] = (bf16_t)((za[kc].y - m_) * rs_);
            af[kc][2] = (bf16_t)((za[kc].z - m_) * rs_);
            af[kc][3] = (bf16_t)((za[kc].w - m_) * rs_);
            af[kc][4] = (bf16_t)((zc[kc].x - m_) * rs_);
            af[kc][5] = (bf16_t)((zc[kc].y - m_) * rs_);
            af[kc][6] = (bf16_t)((zc[kc].z - m_) * rs_);
            af[kc][7] = (bf16_t)((zc[kc].w - m_) * rs_);
        }
        f32x4 acc0 = (f32x4){0.f,0.f,0.f,0.f};
        f32x4 acc1 = (f32x4){0.f,0.f,0.f,0.f};
        f32x4 acc2 = (f32x4){0.f,0.f,0.f,0.f};
        #pragma unroll
        for (int kc = 0; kc < 4; ++kc) {
            acc0 = __builtin_amdgcn_mfma_f32_16x16x32_bf16(af[kc], bfz[0][kc], acc0, 0, 0, 0);
            acc1 = __builtin_amdgcn_mfma_f32_16x16x32_bf16(af[kc], bfz[1][kc], acc1, 0, 0, 0);
            acc2 = __builtin_amdgcn_mfma_f32_16x16x32_bf16(af[kc], bfz[2][kc], acc2, 0, 0, 0);
        }
        const int rowq_ = t_ >> 3;
        const int k0_ = ((t_ & 7) << 4) + kg * 4;
        float4 bw = {acc0[0] + K0, acc0[1] + K0, acc0[2] + K0, acc0[3] + K0};
        *(float4*)&biasT[((size_t)rowq_ * 16 + r16) * 128 + k0_] = bw;
        bf16x4 p1, p2;
        #pragma unroll
        for (int i2 = 0; i2 < 4; ++i2) { p1[i2] = (bf16_t)(acc1[i2] + K1); p2[i2] = (bf16_t)(acc2[i2] + K2); }
        *(bf16x4*)&pzT[((size_t)rowq_ * 32 + r16) * 128 + k0_] = p1;
        *(bf16x4*)&pzT[((size_t)rowq_ * 32 + 16 + r16) * 128 + k0_] = p2;
    }
}

// ---------------------------------------------------------------- attention: one wg per (nblk, head), XCD-swizzled,
// on-the-fly point rotation; per-thread row computation (no rows_s, no initial barrier); async V/bias prefetch
__global__ __launch_bounds__(256, 3) void k_attn4(
    const bf16_t* __restrict__ projb, const float* __restrict__ projp,
    const float* __restrict__ biasT, const float* __restrict__ rots,
    const float* __restrict__ trans, const float* __restrict__ smask,
    const int* __restrict__ kidx, const float* __restrict__ hwraw,
    bf16_t* __restrict__ catb, bf16_t* __restrict__ Pbf)
{
    __shared__ __align__(16) char pool[51840];
    bf16_t (*Qs)[72]   = (bf16_t(*)[72])pool;
    bf16_t (*Ks)[72]   = (bf16_t(*)[72])(pool + 32 * 72 * 2);
    bf16_t (*Vt)[136]  = (bf16_t(*)[136])pool;
    float  (*att)[132] = (float(*)[132])(pool + 26112);
    bf16_t (*Ps)[136]  = (bf16_t(*)[136])(pool + 26112);
    float  (*optmp)[33]= (float(*)[33])(pool + 26112 + 8704);
    float  (*kp_s)[12] = (float(*)[12])(pool + 43008);
    float  (*qp_s)[12] = (float(*)[12])(pool + 49152);
    float*  km_s       = (float*)(pool + 50688);
    float*  qm_s       = (float*)(pool + 51200);

    const int wgid = blockIdx.x;
    const int swz = (wgid & 7) * 256 + (wgid >> 3);
    const int h = swz >> 7;
    const int nblk = swz & 127;
    const int tid = threadIdx.x;
    const int lane = tid & 63;
    const int w = tid >> 6;
    const int rowq0 = nblk * 32;
    const float hw = log1pf(__expf(hwraw[h])) * 0.13608276348795434f;

    // per-thread gather row: tid<128 -> k-row tid (points); tid>=128 -> k-row tid-128 (K,V)
    const int kslot = tid & 127;
    const int ki = kidx[nblk * 128 + kslot];
    const int kvalid = (ki >= 0 && ki < D_N);
    const int myrow = ki < 0 ? 0 : (ki > D_N - 1 ? D_N - 1 : ki);

    // ---- Phase A (no prior barrier): stage Q (all), k-points+rot (tid<128), qp-rot + K + V-prefetch (tid>=128)
    {
        int q = tid >> 3, cg = (tid & 7) * 8;
        *(bf16x8*)&Qs[q][cg] = *(const bf16x8*)(projb + (size_t)(rowq0 + q) * PBW + h * 64 + cg);
    }
    float Rk[9], tk0 = 0.f, tk1 = 0.f, tk2 = 0.f;
    bf16x8 vreg[8];
    if (tid < 128) {
        km_s[tid] = kvalid ? smask[myrow] : 0.0f;
        const float* Rp = rots + (size_t)myrow * 9;
        const float* tp = trans + (size_t)myrow * 3;
        #pragma unroll
        for (int e = 0; e < 9; ++e) Rk[e] = Rp[e];
        tk0 = tp[0]; tk1 = tp[1]; tk2 = tp[2];
        const float* kp = projp + (size_t)myrow * PPW + 192 + h * 36;
        float4 p0 = *(const float4*)kp;
        float4 p1 = *(const float4*)(kp + 4);
        float4 p2 = *(const float4*)(kp + 8);
        float xs[4] = {p0.x, p0.w, p1.z, p2.y};
        float ys[4] = {p0.y, p1.x, p1.w, p2.z};
        float zs[4] = {p0.z, p1.y, p2.x, p2.w};
        #pragma unroll
        for (int p = 0; p < 4; ++p) {
            kp_s[tid][p*3+0] = Rk[0]*xs[p] + Rk[1]*ys[p] + Rk[2]*zs[p] + tk0;
            kp_s[tid][p*3+1] = Rk[3]*xs[p] + Rk[4]*ys[p] + Rk[5]*zs[p] + tk1;
            kp_s[tid][p*3+2] = Rk[6]*xs[p] + Rk[7]*ys[p] + Rk[8]*zs[p] + tk2;
        }
    } else {
        if (tid < 160) qm_s[tid - 128] = smask[rowq0 + tid - 128];
        int j = tid - 128;
        {
            int q = j >> 2, p = j & 3;
            const float* Rp = rots + (size_t)(rowq0 + q) * 9;
            const float* tp = trans + (size_t)(rowq0 + q) * 3;
            const float* qp = projp + (size_t)(rowq0 + q) * PPW + h * 12 + p * 3;
            float x = qp[0], y = qp[1], zc = qp[2];
            qp_s[q][p*3+0] = Rp[0]*x + Rp[1]*y + Rp[2]*zc + tp[0];
            qp_s[q][p*3+1] = Rp[3]*x + Rp[4]*y + Rp[5]*zc + tp[1];
            qp_s[q][p*3+2] = Rp[6]*x + Rp[7]*y + Rp[8]*zc + tp[2];
        }
        {
            const bf16_t* pK = projb + (size_t)myrow * PBW + OFFK + h * 64;
            #pragma unroll
            for (int u = 0; u < 8; ++u)
                *(bf16x8*)&Ks[j][u * 8] = *(const bf16x8*)(pK + u * 8);
        }
        {   // V prefetch (issue early, LDS-write late in phase C)
            const bf16_t* pV = projb + (size_t)myrow * PBW + OFFV + h * 64;
            #pragma unroll
            for (int u4 = 0; u4 < 8; ++u4)
                vreg[u4] = *(const bf16x8*)(pV + u4 * 8);
        }
    }
    float bT_reg[16];
    {
        int q = tid >> 3, kg = tid & 7;
        const float* bT = biasT + ((size_t)(rowq0 + q) * 16 + h) * 128 + kg;
        #pragma unroll
        for (int j2 = 0; j2 < 16; ++j2) bT_reg[j2] = bT[j2 * 8];
    }
    __syncthreads();
    // ---- Phase B: QK^T MFMA
    {
        #pragma unroll
        for (int j = 0; j < 4; ++j) {
            int T = w * 4 + j;
            int m = T & 1, n = T >> 1;
            f32x4 acc = (f32x4){0.f,0.f,0.f,0.f};
            #pragma unroll
            for (int kc = 0; kc < 2; ++kc) {
                bf16x8 a = *(const bf16x8*)&Qs[m*16 + (lane & 15)][kc*32 + (lane >> 4) * 8];
                bf16x8 b = *(const bf16x8*)&Ks[n*16 + (lane & 15)][kc*32 + (lane >> 4) * 8];
                acc = __builtin_amdgcn_mfma_f32_16x16x32_bf16(a, b, acc, 0, 0, 0);
            }
            #pragma unroll
            for (int i = 0; i < 4; ++i)
                att[m*16 + (lane >> 4)*4 + i][n*16 + (lane & 15)] = acc[i];
        }
    }
    __syncthreads();
    // ---- Phase C: write prefetched V^T (tid>=128) + v-points rot->Vt (tid<128) + logit assembly
    if (tid < 128) {
        const float* vp = projp + (size_t)myrow * PPW + 192 + h * 36 + 12;
        float4 a0 = *(const float4*)(vp);
        float4 a1 = *(const float4*)(vp + 4);
        float4 a2 = *(const float4*)(vp + 8);
        float4 a3 = *(const float4*)(vp + 12);
        float4 a4 = *(const float4*)(vp + 16);
        float4 a5 = *(const float4*)(vp + 20);
        float xs[8] = {a0.x, a0.w, a1.z, a2.y, a3.x, a3.w, a4.z, a5.y};
        float ys[8] = {a0.y, a1.x, a1.w, a2.z, a3.y, a4.x, a4.w, a5.z};
        float zs[8] = {a0.z, a1.y, a2.x, a2.w, a3.z, a4.y, a5.x, a5.w};
        #pragma unroll
        for (int p = 0; p < 8; ++p) {
            Vt[64 + p*3 + 0][tid] = (bf16_t)(Rk[0]*xs[p] + Rk[1]*ys[p] + Rk[2]*zs[p] + tk0);
            Vt[64 + p*3 + 1][tid] = (bf16_t)(Rk[3]*xs[p] + Rk[4]*ys[p] + Rk[5]*zs[p] + tk1);
            Vt[64 + p*3 + 2][tid] = (bf16_t)(Rk[6]*xs[p] + Rk[7]*ys[p] + Rk[8]*zs[p] + tk2);
        }
        {
            bf16x8 zz = {};
            *(bf16x8*)&Vt[88 + (tid & 7)][(tid >> 3) * 8] = zz;
        }
    } else {
        int krow = tid - 128;
        #pragma unroll
        for (int u4 = 0; u4 < 8; ++u4) {
            #pragma unroll
            for (int jj = 0; jj < 8; ++jj) Vt[u4 * 8 + jj][krow] = vreg[u4][jj];
        }
    }
    {
        int q = tid >> 3, kg = tid & 7;
        float qp[12];
        #pragma unroll
        for (int e = 0; e < 12; ++e) qp[e] = qp_s[q][e];
        float qm = qm_s[q];
        #pragma unroll
        for (int j2 = 0; j2 < 16; ++j2) {
            int k = kg + j2 * 8;
            float4 k0 = *(const float4*)&kp_s[k][0];
            float4 k1 = *(const float4*)&kp_s[k][4];
            float4 k2 = *(const float4*)&kp_s[k][8];
            float d0 = qp[0]-k0.x, d1 = qp[1]-k0.y, d2_ = qp[2]-k0.z, d3 = qp[3]-k0.w;
            float d4 = qp[4]-k1.x, d5 = qp[5]-k1.y, d6 = qp[6]-k1.z, d7 = qp[7]-k1.w;
            float d8 = qp[8]-k2.x, d9 = qp[9]-k2.y, d10 = qp[10]-k2.z, d11 = qp[11]-k2.w;
            float dd = d0*d0+d1*d1+d2_*d2_+d3*d3+d4*d4+d5*d5+d6*d6+d7*d7+d8*d8+d9*d9+d10*d10+d11*d11;
            float val = att[q][k] * 0.07216878364870323f
                      + 0.5773502691896258f * bT_reg[j2]
                      + 100000.0f * (qm * km_s[k] - 1.0f)
                      - 0.5f * hw * dd;
            att[q][k] = val;
        }
    }
    __syncthreads();
    // ---- Phase D: softmax; then (after barrier, att dead) write P into overlaid Ps region + global
    {
        int q = tid >> 3, kg = tid & 7;
        float l[16];
        #pragma unroll
        for (int j2 = 0; j2 < 16; ++j2) l[j2] = att[q][kg + j2 * 8];
        float mx = l[0];
        #pragma unroll
        for (int j2 = 1; j2 < 16; ++j2) mx = fmaxf(mx, l[j2]);
        mx = fmaxf(mx, __shfl_xor(mx, 1));
        mx = fmaxf(mx, __shfl_xor(mx, 2));
        mx = fmaxf(mx, __shfl_xor(mx, 4));
        float se = 0.f;
        #pragma unroll
        for (int j2 = 0; j2 < 16; ++j2) { l[j2] = __expf(l[j2] - mx); se += l[j2]; }
        se += __shfl_xor(se, 1);
        se += __shfl_xor(se, 2);
        se += __shfl_xor(se, 4);
        float inv = 1.0f / se;
        __syncthreads();   // all att reads complete before Ps (same bytes) is written
        bf16_t* pg = Pbf + ((size_t)(rowq0 + q) * 16 + h) * 128;
        #pragma unroll
        for (int j2 = 0; j2 < 16; ++j2) {
            bf16_t pb = (bf16_t)(l[j2] * inv);
            Ps[q][kg + j2 * 8] = pb;
            pg[kg + j2 * 8] = pb;
        }
    }
    __syncthreads();
    // ---- Phase E: PV MFMA
    {
        #pragma unroll
        for (int j = 0; j < 3; ++j) {
            int T = w * 3 + j;
            int m = T & 1, n = T >> 1;
            f32x4 acc = (f32x4){0.f,0.f,0.f,0.f};
            #pragma unroll
            for (int kc = 0; kc < 4; ++kc) {
                bf16x8 a = *(const bf16x8*)&Ps[m*16 + (lane & 15)][kc*32 + (lane >> 4) * 8];
                bf16x8 b = *(const bf16x8*)&Vt[n*16 + (lane & 15)][kc*32 + (lane >> 4) * 8];
                acc = __builtin_amdgcn_mfma_f32_16x16x32_bf16(a, b, acc, 0, 0, 0);
            }
            int rowb = m * 16 + (lane >> 4) * 4;
            int col = lane & 15;
            if (n < 4) {
                #pragma unroll
                for (int i = 0; i < 4; ++i)
                    catb[(size_t)(rowq0 + rowb + i) * CATW + h * 64 + n * 16 + col] = (bf16_t)acc[i];
            } else {
                #pragma unroll
                for (int i = 0; i < 4; ++i)
                    optmp[rowb + i][(n - 4) * 16 + col] = acc[i];
            }
        }
    }
    __syncthreads();
    // ---- Phase F: o_pt inverse transform + norm
    {
        int q = tid >> 3, pp = tid & 7;
        float sx = optmp[q][pp * 3 + 0];
        float sy = optmp[q][pp * 3 + 1];
        float sz = optmp[q][pp * 3 + 2];
        const float* R = rots + (size_t)(rowq0 + q) * 9;
        const float* t = trans + (size_t)(rowq0 + q) * 3;
        float x = sx - t[0], y = sy - t[1], z2 = sz - t[2];
        float ox = R[0] * x + R[3] * y + R[6] * z2;
        float oy = R[1] * x + R[4] * y + R[7] * z2;
        float oz = R[2] * x + R[5] * y + R[8] * z2;
        bf16_t* cp = catb + (size_t)(rowq0 + q) * CATW;
        cp[1024 + h * 24 + pp * 3 + 0] = (bf16_t)ox;
        cp[1024 + h * 24 + pp * 3 + 1] = (bf16_t)oy;
        cp[1024 + h * 24 + pp * 3 + 2] = (bf16_t)oz;
        cp[1408 + h * 8 + pp] = (bf16_t)sqrtf(ox * ox + oy * oy + oz * oz + 1e-8f);
    }
}

// ---------------------------------------------------------------- o_pair: per rowq MFMA [16h x 128k] x [128k x 32c]
__global__ __launch_bounds__(256) void k_opair(const bf16_t* __restrict__ Pbf,
    const bf16_t* __restrict__ pzT, bf16_t* __restrict__ catb)
{
    int tid = threadIdx.x, lane = tid & 63, w = tid >> 6;
    size_t rowq = (size_t)blockIdx.x * 4 + w;
    const bf16_t* Pp = Pbf + rowq * 2048;
    const bf16_t* zp = pzT + rowq * 4096;
    bf16x8 pa[4];
    #pragma unroll
    for (int kc = 0; kc < 4; ++kc)
        pa[kc] = *(const bf16x8*)(Pp + (size_t)(lane & 15) * 128 + kc * 32 + (lane >> 4) * 8);
    #pragma unroll
    for (int ct = 0; ct < 2; ++ct) {
        f32x4 acc = (f32x4){0.f,0.f,0.f,0.f};
        #pragma unroll
        for (int kc = 0; kc < 4; ++kc) {
            bf16x8 b = *(const bf16x8*)(zp + (size_t)(ct * 16 + (lane & 15)) * 128 + kc * 32 + (lane >> 4) * 8);
            acc = __builtin_amdgcn_mfma_f32_16x16x32_bf16(pa[kc], b, acc, 0, 0, 0);
        }
        #pragma unroll
        for (int i = 0; i < 4; ++i) {
            int hh = (lane >> 4) * 4 + i;
            catb[rowq * CATW + 1536 + hh * 32 + ct * 16 + (lane & 15)] = (bf16_t)acc[i];
        }
    }
}

// ---------------------------------------------------------------- out GEMM, 64x128 tile, XCD-friendly flat id
__global__ __launch_bounds__(256) void gemm_out(const bf16_t* __restrict__ A, const bf16_t* __restrict__ BT,
    float* __restrict__ C)
{
    __shared__ bf16_t Asl[64][32];
    __shared__ bf16_t Bsl[128][32];
    const int tid = threadIdx.x, lane = tid & 63, w = tid >> 6;
    const int by = blockIdx.x & 63, bxc = blockIdx.x >> 6;
    const int row0 = by * 64, col0 = bxc * 128;
    const int wr = (w >> 1) * 32, wc = (w & 1) * 64;
    const int K = 2048;
    const int sr = lane >> 2, k8 = (lane & 3) * 8;
    const bf16_t* Ab = A + (size_t)(row0 + w * 16 + sr) * K + k8;
    const bf16_t* Bb = BT + (size_t)(col0 + w * 32 + sr) * K + k8;
    f32x4 acc[2][4];
    #pragma unroll
    for (int m = 0; m < 2; ++m)
        #pragma unroll
        for (int n = 0; n < 4; ++n) acc[m][n] = (f32x4){0.f,0.f,0.f,0.f};
    for (int k0 = 0; k0 < K; k0 += 32) {
        __syncthreads();
        gld16(Ab + k0,          &Asl[w * 16][0]);
        gld16(Bb + k0,          &Bsl[w * 32][0]);
        gld16(Bb + k0 + 16 * K, &Bsl[w * 32 + 16][0]);
        __syncthreads();
        bf16x8 af[2], bfr[4];
        #pragma unroll
        for (int m = 0; m < 2; ++m) af[m]  = *(const bf16x8*)&Asl[wr + m*16 + (lane & 15)][(lane >> 4) * 8];
        #pragma unroll
        for (int n = 0; n < 4; ++n) bfr[n] = *(const bf16x8*)&Bsl[wc + n*16 + (lane & 15)][(lane >> 4) * 8];
        #pragma unroll
        for (int m = 0; m < 2; ++m)
            #pragma unroll
            for (int n = 0; n < 4; ++n)
                acc[m][n] = __builtin_amdgcn_mfma_f32_16x16x32_bf16(af[m], bfr[n], acc[m][n], 0, 0, 0);
    }
    #pragma unroll
    for (int m = 0; m < 2; ++m)
        #pragma unroll
        for (int n = 0; n < 4; ++n)
            #pragma unroll
            for (int i = 0; i < 4; ++i)
                C[(size_t)(row0 + wr + m*16 + (lane >> 4)*4 + i) * 512 + col0 + wc + n*16 + (lane & 15)] = acc[m][n][i];
}

// ---------------------------------------------------------------- launcher
extern "C" void kernel_launch(void* const* d_in, const int* in_sizes, int n_in,
                              void* d_out, int out_size, void* d_ws, size_t ws_size,
                              hipStream_t stream)
{
    (void)in_sizes; (void)n_in; (void)out_size;
    const float* s     = (const float*)d_in[0];
    const float* z     = (const float*)d_in[1];
    const float* trans = (const float*)d_in[2];
    const float* rots  = (const float*)d_in[3];
    const float* smask = (const float*)d_in[4];
    const int*   kidx  = (const int*)d_in[5];
    const float* Wq    = (const float*)d_in[6];
    const float* Wk    = (const float*)d_in[7];
    const float* Wv    = (const float*)d_in[8];
    const float* Wqp   = (const float*)d_in[9];
    const float* Wkvp  = (const float*)d_in[10];
    const float* Wb    = (const float*)d_in[11];
    const float* Wdz   = (const float*)d_in[12];
    const float* hw    = (const float*)d_in[13];
    const float* Wout  = (const float*)d_in[14];
    const float* g_s   = (const float*)d_in[15];
    const float* b_s   = (const float*)d_in[16];
    const float* g_z   = (const float*)d_in[17];
    const float* b_z   = (const float*)d_in[18];

    char* ws = (char*)d_ws;
    bf16_t* projb = (bf16_t*)(ws);                      // 25,165,824
    float*  projp = (float*)(ws + 25165824);            // 12,582,912
    float*  biasT = (float*)(ws + 37748736);            // 33,554,432
    bf16_t* wcatT = (bf16_t*)(ws + 71303168);           //  3,932,160
    bf16_t* s_nb  = (bf16_t*)(ws + 75235328);           //  4,194,304
    bf16_t* pzT   = (bf16_t*)(ws + 79429632);           // 33,554,432
    bf16_t* Pbf   = (bf16_t*)(ws + 112984064);          // 16,777,216
    bf16_t* catb  = (bf16_t*)(ws + 129761280);          // 16,777,216
    bf16_t* WoutT = (bf16_t*)(ws + 146538496);          //  2,097,152
    bf16_t* WzT   = (bf16_t*)(ws + 148635648);          //     12,288
    float*  Kv    = (float*)(ws + 148647936);           //        192
    if (ws_size < (size_t)148648128) return;
    float* out = (float*)d_out;

    k_prep<<<1761, 256, 0, stream>>>(Wq, Wk, Wv, Wqp, Wkvp, Wout, Wb, Wdz, g_z, b_z,
                                     s, g_s, b_s, wcatT, WoutT, WzT, Kv, s_nb);
    k_fused<<<3008, 256, 0, stream>>>(s_nb, wcatT, projb, projp, z, WzT, Kv, biasT, pzT);
    k_attn4<<<2048, 256, 0, stream>>>(projb, projp, biasT, rots, trans, smask, kidx, hw, catb, Pbf);
    k_opair<<<1024, 256, 0, stream>>>(Pbf, pzT, catb);
    gemm_out<<<256, 256, 0, stream>>>(catb, WoutT, out);
}

// Round 14
// 201.998 us; speedup vs baseline: 1.1018x; 1.0225x over previous
//
#include <hip/hip_runtime.h>
#include <math.h>

#define D_N 4096
#define PBW 3072
#define PPW 768
#define OFFK 1024
#define OFFV 2048
#define CATW 2048

typedef __bf16 bf16_t;
typedef __bf16 bf16x8 __attribute__((ext_vector_type(8)));
typedef __bf16 bf16x4 __attribute__((ext_vector_type(4)));
typedef float f32x4 __attribute__((ext_vector_type(4)));

__device__ __forceinline__ void gld16(const void* g, void* l) {
    __builtin_amdgcn_global_load_lds((const __attribute__((address_space(1))) unsigned int*)g,
                                     (__attribute__((address_space(3))) unsigned int*)l, 16, 0, 0);
}

// ---------------------------------------------------------------- merged prep:
// blocks [0,480): wcatT ; [480,736): WoutT ; 736: WzT+Kv ; [737,1761): ln_s
__global__ __launch_bounds__(256) void k_prep(
    const float* __restrict__ Wq, const float* __restrict__ Wk, const float* __restrict__ Wv,
    const float* __restrict__ Wqp, const float* __restrict__ Wkvp, const float* __restrict__ Wout,
    const float* __restrict__ Wb, const float* __restrict__ Wdz,
    const float* __restrict__ gz, const float* __restrict__ bz,
    const float* __restrict__ s, const float* __restrict__ g_s, const float* __restrict__ b_s,
    bf16_t* __restrict__ wcatT, bf16_t* __restrict__ WoutT,
    bf16_t* __restrict__ WzT, float* __restrict__ Kv, bf16_t* __restrict__ s_nb)
{
    __shared__ float T[64][65];
    const int bx = blockIdx.x;
    const int tid = threadIdx.x;
    if (bx < 736) {
        const float* src; int ld, coff, r0;
        bf16_t* dst; int Rdst;
        if (bx < 480) {
            int c0 = (bx % 60) * 64;
            r0 = (bx / 60) * 64;
            if (c0 < 1024)      { src = Wq;   ld = 1024; coff = c0; }
            else if (c0 < 2048) { src = Wk;   ld = 1024; coff = c0 - 1024; }
            else if (c0 < 3072) { src = Wv;   ld = 1024; coff = c0 - 2048; }
            else if (c0 < 3264) { src = Wqp;  ld = 192;  coff = c0 - 3072; }
            else                { src = Wkvp; ld = 576;  coff = c0 - 3264; }
            dst = wcatT + (size_t)c0 * 512; Rdst = 512;
        } else {
            int b = bx - 480;
            int c0 = (b & 7) * 64;
            r0 = (b >> 3) * 64;
            src = Wout; ld = 512; coff = c0;
            dst = WoutT + (size_t)c0 * 2048; Rdst = 2048;
        }
        {
            int rr = tid >> 2, cb = (tid & 3) * 16;
            const float* p = src + (size_t)(r0 + rr) * ld + coff + cb;
            #pragma unroll
            for (int i = 0; i < 4; ++i)
                *(float4*)&T[rr][cb + i * 4] = *(const float4*)(p + i * 4);
        }
        __syncthreads();
        {
            int cc = tid >> 2, rb = (tid & 3) * 16;
            bf16_t* o = dst + (size_t)cc * Rdst + r0 + rb;
            bf16x8 o0, o1;
            #pragma unroll
            for (int j = 0; j < 8; ++j) o0[j] = (bf16_t)T[rb + j][cc];
            #pragma unroll
            for (int j = 0; j < 8; ++j) o1[j] = (bf16_t)T[rb + 8 + j][cc];
            *(bf16x8*)(o) = o0;
            *(bf16x8*)(o + 8) = o1;
        }
    } else if (bx == 736) {
        for (int i = tid; i < 6144; i += 256) {
            int j = i >> 7, c = i & 127;
            float w = (j < 16) ? Wb[c * 16 + j] : Wdz[c * 32 + (j - 16)];
            WzT[i] = (bf16_t)(gz[c] * w);
        }
        if (tid < 48) {
            int j = tid;
            float acc = 0.f;
            for (int c = 0; c < 128; ++c) {
                float w = (j < 16) ? Wb[c * 16 + j] : Wdz[c * 32 + (j - 16)];
                acc += bz[c] * w;
            }
            Kv[j] = acc;
        }
    } else {
        int row = (bx - 737) * 4 + (tid >> 6);
        int lane = tid & 63;
        const float4* p = (const float4*)(s + (size_t)row * 512);
        float4 v0 = p[lane];
        float4 v1 = p[lane + 64];
        float sum = v0.x + v0.y + v0.z + v0.w + v1.x + v1.y + v1.z + v1.w;
        float sq  = v0.x*v0.x + v0.y*v0.y + v0.z*v0.z + v0.w*v0.w
                  + v1.x*v1.x + v1.y*v1.y + v1.z*v1.z + v1.w*v1.w;
        #pragma unroll
        for (int off = 1; off < 64; off <<= 1) {
            sum += __shfl_xor(sum, off);
            sq  += __shfl_xor(sq, off);
        }
        float m = sum * (1.0f / 512.0f);
        float var = sq * (1.0f / 512.0f) - m * m;
        float rs = rsqrtf(var + 1e-5f);
        int c = lane * 4;
        int c2 = 256 + lane * 4;
        bf16x4 r0, r1;
        r0[0] = (bf16_t)((v0.x - m) * rs * g_s[c+0] + b_s[c+0]);
        r0[1] = (bf16_t)((v0.y - m) * rs * g_s[c+1] + b_s[c+1]);
        r0[2] = (bf16_t)((v0.z - m) * rs * g_s[c+2] + b_s[c+2]);
        r0[3] = (bf16_t)((v0.w - m) * rs * g_s[c+3] + b_s[c+3]);
        r1[0] = (bf16_t)((v1.x - m) * rs * g_s[c2+0] + b_s[c2+0]);
        r1[1] = (bf16_t)((v1.y - m) * rs * g_s[c2+1] + b_s[c2+1]);
        r1[2] = (bf16_t)((v1.z - m) * rs * g_s[c2+2] + b_s[c2+2]);
        r1[3] = (bf16_t)((v1.w - m) * rs * g_s[c2+3] + b_s[c2+3]);
        *(bf16x4*)(s_nb + (size_t)row * 512 + c)  = r0;
        *(bf16x4*)(s_nb + (size_t)row * 512 + c2) = r1;
    }
}

// ---------------------------------------------------------------- fused: proj GEMM (960 blocks, 16KB LDS) +
// z LN/proj (2048 blocks, REGISTER-resident); biasT now bf16
__global__ __launch_bounds__(256) void k_fused(
    const bf16_t* __restrict__ A, const bf16_t* __restrict__ BT,
    bf16_t* __restrict__ projb, float* __restrict__ projp,
    const float* __restrict__ z, const bf16_t* __restrict__ WzT, const float* __restrict__ Kv,
    bf16_t* __restrict__ biasT, bf16_t* __restrict__ pzT)
{
    __shared__ bf16_t Asl[128][32];
    __shared__ bf16_t Bsl[128][32];
    const int bx = blockIdx.x;
    const int tid = threadIdx.x, lane = tid & 63, w = tid >> 6;
    int gemm_id = -1, zid = 0;
    if (bx < 2880) {
        int s3 = bx % 3, b3 = bx / 3;
        if (s3 == 0) gemm_id = b3;
        else         zid = b3 * 2 + s3 - 1;
    } else {
        zid = 1920 + (bx - 2880);
    }

    if (gemm_id >= 0) {
        const int row0 = (gemm_id / 30) * 128, col0 = (gemm_id % 30) * 128;
        const int wr = (w >> 1) * 64, wc = (w & 1) * 64;
        const int K = 512;
        const int sr = lane >> 2, k8 = (lane & 3) * 8;
        const bf16_t* Ab = A + (size_t)(row0 + w * 32 + sr) * K + k8;
        const bf16_t* Bb = BT + (size_t)(col0 + w * 32 + sr) * K + k8;
        f32x4 acc[4][4];
        #pragma unroll
        for (int m = 0; m < 4; ++m)
            #pragma unroll
            for (int n = 0; n < 4; ++n) acc[m][n] = (f32x4){0.f,0.f,0.f,0.f};
        for (int k0 = 0; k0 < K; k0 += 32) {
            __syncthreads();
            gld16(Ab + k0,          &Asl[w * 32][0]);
            gld16(Ab + k0 + 16 * K, &Asl[w * 32 + 16][0]);
            gld16(Bb + k0,          &Bsl[w * 32][0]);
            gld16(Bb + k0 + 16 * K, &Bsl[w * 32 + 16][0]);
            __syncthreads();
            bf16x8 af[4], bfr[4];
            #pragma unroll
            for (int m = 0; m < 4; ++m) af[m]  = *(const bf16x8*)&Asl[wr + m*16 + (lane & 15)][(lane >> 4) * 8];
            #pragma unroll
            for (int n = 0; n < 4; ++n) bfr[n] = *(const bf16x8*)&Bsl[wc + n*16 + (lane & 15)][(lane >> 4) * 8];
            #pragma unroll
            for (int m = 0; m < 4; ++m)
                #pragma unroll
                for (int n = 0; n < 4; ++n)
                    acc[m][n] = __builtin_amdgcn_mfma_f32_16x16x32_bf16(af[m], bfr[n], acc[m][n], 0, 0, 0);
        }
        if (col0 < 3072) {
            #pragma unroll
            for (int m = 0; m < 4; ++m)
                #pragma unroll
                for (int n = 0; n < 4; ++n)
                    #pragma unroll
                    for (int i = 0; i < 4; ++i)
                        projb[(size_t)(row0 + wr + m*16 + (lane >> 4)*4 + i) * PBW + col0 + wc + n*16 + (lane & 15)]
                            = (bf16_t)acc[m][n][i];
        } else {
            #pragma unroll
            for (int m = 0; m < 4; ++m)
                #pragma unroll
                for (int n = 0; n < 4; ++n)
                    #pragma unroll
                    for (int i = 0; i < 4; ++i)
                        projp[(size_t)(row0 + wr + m*16 + (lane >> 4)*4 + i) * PPW + col0 - 3072 + wc + n*16 + (lane & 15)]
                            = acc[m][n][i];
        }
        return;
    }

    // ---------------- z LN + projection branch: register-resident, compiler-managed waits
    const int r16 = lane & 15, kg = lane >> 4;
    bf16x8 bfz[3][4];
    #pragma unroll
    for (int nt = 0; nt < 3; ++nt)
        #pragma unroll
        for (int kc = 0; kc < 4; ++kc)
            bfz[nt][kc] = *(const bf16x8*)(WzT + (size_t)(nt * 16 + r16) * 128 + kc * 32 + kg * 8);
    const float K0 = Kv[r16], K1 = Kv[16 + r16], K2 = Kv[32 + r16];
    const int gid = zid * 4 + w;

    #pragma unroll 2
    for (int it = 0; it < 4; ++it) {
        const int t_ = gid * 4 + it;
        const float* zp = z + ((size_t)t_ * 16 + r16) * 128 + kg * 8;
        float4 za[4], zc[4];
        float sum = 0.f, sq = 0.f;
        #pragma unroll
        for (int kc = 0; kc < 4; ++kc) {
            za[kc] = *(const float4*)(zp + kc * 32);
            zc[kc] = *(const float4*)(zp + kc * 32 + 4);
            sum += za[kc].x + za[kc].y + za[kc].z + za[kc].w + zc[kc].x + zc[kc].y + zc[kc].z + zc[kc].w;
            sq  += za[kc].x*za[kc].x + za[kc].y*za[kc].y + za[kc].z*za[kc].z + za[kc].w*za[kc].w
                 + zc[kc].x*zc[kc].x + zc[kc].y*zc[kc].y + zc[kc].z*zc[kc].z + zc[kc].w*zc[kc].w;
        }
        sum += __shfl_xor(sum, 16); sq += __shfl_xor(sq, 16);
        sum += __shfl_xor(sum, 32); sq += __shfl_xor(sq, 32);
        float m_ = sum * (1.0f / 128.0f);
        float rs_ = rsqrtf(sq * (1.0f / 128.0f) - m_ * m_ + 1e-5f);
        bf16x8 af[4];
        #pragma unroll
        for (int kc = 0; kc < 4; ++kc) {
            af[kc][0] = (bf16_t)((za[kc].x - m_) * rs_);
            af[kc][1] = (bf16_t)((za[kc].y - m_) * rs_);
            af[kc][2] = (bf16_t)((za[kc].z - m_) * rs_);
            af[kc][3] = (bf16_t)((za[kc].w - m_) * rs_);
            af[kc][4] = (bf16_t)((zc[kc].x - m_) * rs_);
            af[kc][5] = (bf16_t)((zc[kc].y - m_) * rs_);
            af[kc][6] = (bf16_t)((zc[kc].z - m_) * rs_);
            af[kc][7] = (bf16_t)((zc[kc].w - m_) * rs_);
        }
        f32x4 acc0 = (f32x4){0.f,0.f,0.f,0.f};
        f32x4 acc1 = (f32x4){0.f,0.f,0.f,0.f};
        f32x4 acc2 = (f32x4){0.f,0.f,0.f,0.f};
        #pragma unroll
        for (int kc = 0; kc < 4; ++kc) {
            acc0 = __builtin_amdgcn_mfma_f32_16x16x32_bf16(af[kc], bfz[0][kc], acc0, 0, 0, 0);
            acc1 = __builtin_amdgcn_mfma_f32_16x16x32_bf16(af[kc], bfz[1][kc], acc1, 0, 0, 0);
            acc2 = __builtin_amdgcn_mfma_f32_16x16x32_bf16(af[kc], bfz[2][kc], acc2, 0, 0, 0);
        }
        const int rowq_ = t_ >> 3;
        const int k0_ = ((t_ & 7) << 4) + kg * 4;
        bf16x4 bb, p1, p2;
        #pragma unroll
        for (int i2 = 0; i2 < 4; ++i2) {
            bb[i2] = (bf16_t)(acc0[i2] + K0);
            p1[i2] = (bf16_t)(acc1[i2] + K1);
            p2[i2] = (bf16_t)(acc2[i2] + K2);
        }
        *(bf16x4*)&biasT[((size_t)rowq_ * 16 + r16) * 128 + k0_] = bb;
        *(bf16x4*)&pzT[((size_t)rowq_ * 32 + r16) * 128 + k0_] = p1;
        *(bf16x4*)&pzT[((size_t)rowq_ * 32 + 16 + r16) * 128 + k0_] = p2;
    }
}

// ---------------------------------------------------------------- attention: one wg per (nblk, head), XCD-swizzled,
// on-the-fly point rotation; per-thread gather rows; async V/bias prefetch; vectorized P stores
__global__ __launch_bounds__(256, 3) void k_attn4(
    const bf16_t* __restrict__ projb, const float* __restrict__ projp,
    const bf16_t* __restrict__ biasT, const float* __restrict__ rots,
    const float* __restrict__ trans, const float* __restrict__ smask,
    const int* __restrict__ kidx, const float* __restrict__ hwraw,
    bf16_t* __restrict__ catb, bf16_t* __restrict__ Pbf)
{
    __shared__ __align__(16) char pool[51840];
    bf16_t (*Qs)[72]   = (bf16_t(*)[72])pool;
    bf16_t (*Ks)[72]   = (bf16_t(*)[72])(pool + 32 * 72 * 2);
    bf16_t (*Vt)[136]  = (bf16_t(*)[136])pool;
    float  (*att)[132] = (float(*)[132])(pool + 26112);
    bf16_t (*Ps)[136]  = (bf16_t(*)[136])(pool + 26112);
    float  (*optmp)[33]= (float(*)[33])(pool + 26112 + 8704);
    float  (*kp_s)[12] = (float(*)[12])(pool + 43008);
    float  (*qp_s)[12] = (float(*)[12])(pool + 49152);
    float*  km_s       = (float*)(pool + 50688);
    float*  qm_s       = (float*)(pool + 51200);

    const int wgid = blockIdx.x;
    const int swz = (wgid & 7) * 256 + (wgid >> 3);
    const int h = swz >> 7;
    const int nblk = swz & 127;
    const int tid = threadIdx.x;
    const int lane = tid & 63;
    const int w = tid >> 6;
    const int rowq0 = nblk * 32;
    const float hw = log1pf(__expf(hwraw[h])) * 0.13608276348795434f;

    const int kslot = tid & 127;
    const int ki = kidx[nblk * 128 + kslot];
    const int kvalid = (ki >= 0 && ki < D_N);
    const int myrow = ki < 0 ? 0 : (ki > D_N - 1 ? D_N - 1 : ki);

    // ---- Phase A: stage Q (all), k-points+rot (tid<128), qp-rot + K + V-prefetch (tid>=128)
    {
        int q = tid >> 3, cg = (tid & 7) * 8;
        *(bf16x8*)&Qs[q][cg] = *(const bf16x8*)(projb + (size_t)(rowq0 + q) * PBW + h * 64 + cg);
    }
    float Rk[9], tk0 = 0.f, tk1 = 0.f, tk2 = 0.f;
    bf16x8 vreg[8];
    if (tid < 128) {
        km_s[tid] = kvalid ? smask[myrow] : 0.0f;
        const float* Rp = rots + (size_t)myrow * 9;
        const float* tp = trans + (size_t)myrow * 3;
        #pragma unroll
        for (int e = 0; e < 9; ++e) Rk[e] = Rp[e];
        tk0 = tp[0]; tk1 = tp[1]; tk2 = tp[2];
        const float* kp = projp + (size_t)myrow * PPW + 192 + h * 36;
        float4 p0 = *(const float4*)kp;
        float4 p1 = *(const float4*)(kp + 4);
        float4 p2 = *(const float4*)(kp + 8);
        float xs[4] = {p0.x, p0.w, p1.z, p2.y};
        float ys[4] = {p0.y, p1.x, p1.w, p2.z};
        float zs[4] = {p0.z, p1.y, p2.x, p2.w};
        #pragma unroll
        for (int p = 0; p < 4; ++p) {
            kp_s[tid][p*3+0] = Rk[0]*xs[p] + Rk[1]*ys[p] + Rk[2]*zs[p] + tk0;
            kp_s[tid][p*3+1] = Rk[3]*xs[p] + Rk[4]*ys[p] + Rk[5]*zs[p] + tk1;
            kp_s[tid][p*3+2] = Rk[6]*xs[p] + Rk[7]*ys[p] + Rk[8]*zs[p] + tk2;
        }
    } else {
        if (tid < 160) qm_s[tid - 128] = smask[rowq0 + tid - 128];
        int j = tid - 128;
        {
            int q = j >> 2, p = j & 3;
            const float* Rp = rots + (size_t)(rowq0 + q) * 9;
            const float* tp = trans + (size_t)(rowq0 + q) * 3;
            const float* qp = projp + (size_t)(rowq0 + q) * PPW + h * 12 + p * 3;
            float x = qp[0], y = qp[1], zc = qp[2];
            qp_s[q][p*3+0] = Rp[0]*x + Rp[1]*y + Rp[2]*zc + tp[0];
            qp_s[q][p*3+1] = Rp[3]*x + Rp[4]*y + Rp[5]*zc + tp[1];
            qp_s[q][p*3+2] = Rp[6]*x + Rp[7]*y + Rp[8]*zc + tp[2];
        }
        {
            const bf16_t* pK = projb + (size_t)myrow * PBW + OFFK + h * 64;
            #pragma unroll
            for (int u = 0; u < 8; ++u)
                *(bf16x8*)&Ks[j][u * 8] = *(const bf16x8*)(pK + u * 8);
        }
        {
            const bf16_t* pV = projb + (size_t)myrow * PBW + OFFV + h * 64;
            #pragma unroll
            for (int u4 = 0; u4 < 8; ++u4)
                vreg[u4] = *(const bf16x8*)(pV + u4 * 8);
        }
    }
    float bT_reg[16];
    {
        int q = tid >> 3, kg = tid & 7;
        const bf16_t* bT = biasT + ((size_t)(rowq0 + q) * 16 + h) * 128 + kg;
        #pragma unroll
        for (int j2 = 0; j2 < 16; ++j2) bT_reg[j2] = (float)bT[j2 * 8];
    }
    __syncthreads();
    // ---- Phase B: QK^T MFMA
    {
        #pragma unroll
        for (int j = 0; j < 4; ++j) {
            int T = w * 4 + j;
            int m = T & 1, n = T >> 1;
            f32x4 acc = (f32x4){0.f,0.f,0.f,0.f};
            #pragma unroll
            for (int kc = 0; kc < 2; ++kc) {
                bf16x8 a = *(const bf16x8*)&Qs[m*16 + (lane & 15)][kc*32 + (lane >> 4) * 8];
                bf16x8 b = *(const bf16x8*)&Ks[n*16 + (lane & 15)][kc*32 + (lane >> 4) * 8];
                acc = __builtin_amdgcn_mfma_f32_16x16x32_bf16(a, b, acc, 0, 0, 0);
            }
            #pragma unroll
            for (int i = 0; i < 4; ++i)
                att[m*16 + (lane >> 4)*4 + i][n*16 + (lane & 15)] = acc[i];
        }
    }
    __syncthreads();
    // ---- Phase C: write prefetched V^T (tid>=128) + v-points rot->Vt (tid<128) + logit assembly
    if (tid < 128) {
        const float* vp = projp + (size_t)myrow * PPW + 192 + h * 36 + 12;
        float4 a0 = *(const float4*)(vp);
        float4 a1 = *(const float4*)(vp + 4);
        float4 a2 = *(const float4*)(vp + 8);
        float4 a3 = *(const float4*)(vp + 12);
        float4 a4 = *(const float4*)(vp + 16);
        float4 a5 = *(const float4*)(vp + 20);
        float xs[8] = {a0.x, a0.w, a1.z, a2.y, a3.x, a3.w, a4.z, a5.y};
        float ys[8] = {a0.y, a1.x, a1.w, a2.z, a3.y, a4.x, a4.w, a5.z};
        float zs[8] = {a0.z, a1.y, a2.x, a2.w, a3.z, a4.y, a5.x, a5.w};
        #pragma unroll
        for (int p = 0; p < 8; ++p) {
            Vt[64 + p*3 + 0][tid] = (bf16_t)(Rk[0]*xs[p] + Rk[1]*ys[p] + Rk[2]*zs[p] + tk0);
            Vt[64 + p*3 + 1][tid] = (bf16_t)(Rk[3]*xs[p] + Rk[4]*ys[p] + Rk[5]*zs[p] + tk1);
            Vt[64 + p*3 + 2][tid] = (bf16_t)(Rk[6]*xs[p] + Rk[7]*ys[p] + Rk[8]*zs[p] + tk2);
        }
        {
            bf16x8 zz = {};
            *(bf16x8*)&Vt[88 + (tid & 7)][(tid >> 3) * 8] = zz;
        }
    } else {
        int krow = tid - 128;
        #pragma unroll
        for (int u4 = 0; u4 < 8; ++u4) {
            #pragma unroll
            for (int jj = 0; jj < 8; ++jj) Vt[u4 * 8 + jj][krow] = vreg[u4][jj];
        }
    }
    {
        int q = tid >> 3, kg = tid & 7;
        float qp[12];
        #pragma unroll
        for (int e = 0; e < 12; ++e) qp[e] = qp_s[q][e];
        float qm = qm_s[q];
        #pragma unroll
        for (int j2 = 0; j2 < 16; ++j2) {
            int k = kg + j2 * 8;
            float4 k0 = *(const float4*)&kp_s[k][0];
            float4 k1 = *(const float4*)&kp_s[k][4];
            float4 k2 = *(const float4*)&kp_s[k][8];
            float d0 = qp[0]-k0.x, d1 = qp[1]-k0.y, d2_ = qp[2]-k0.z, d3 = qp[3]-k0.w;
            float d4 = qp[4]-k1.x, d5 = qp[5]-k1.y, d6 = qp[6]-k1.z, d7 = qp[7]-k1.w;
            float d8 = qp[8]-k2.x, d9 = qp[9]-k2.y, d10 = qp[10]-k2.z, d11 = qp[11]-k2.w;
            float dd = d0*d0+d1*d1+d2_*d2_+d3*d3+d4*d4+d5*d5+d6*d6+d7*d7+d8*d8+d9*d9+d10*d10+d11*d11;
            float val = att[q][k] * 0.07216878364870323f
                      + 0.5773502691896258f * bT_reg[j2]
                      + 100000.0f * (qm * km_s[k] - 1.0f)
                      - 0.5f * hw * dd;
            att[q][k] = val;
        }
    }
    __syncthreads();
    // ---- Phase D: softmax (consecutive-k ownership) -> vectorized P stores (LDS + global)
    {
        int q = tid >> 3, kg = tid & 7;
        float l[16];
        #pragma unroll
        for (int j2 = 0; j2 < 16; ++j2) l[j2] = att[q][kg * 16 + j2];
        float mx = l[0];
        #pragma unroll
        for (int j2 = 1; j2 < 16; ++j2) mx = fmaxf(mx, l[j2]);
        mx = fmaxf(mx, __shfl_xor(mx, 1));
        mx = fmaxf(mx, __shfl_xor(mx, 2));
        mx = fmaxf(mx, __shfl_xor(mx, 4));
        float se = 0.f;
        #pragma unroll
        for (int j2 = 0; j2 < 16; ++j2) { l[j2] = __expf(l[j2] - mx); se += l[j2]; }
        se += __shfl_xor(se, 1);
        se += __shfl_xor(se, 2);
        se += __shfl_xor(se, 4);
        float inv = 1.0f / se;
        __syncthreads();   // all att reads complete before Ps (same bytes) is written
        bf16_t* pg = Pbf + ((size_t)(rowq0 + q) * 16 + h) * 128 + kg * 16;
        #pragma unroll
        for (int j4 = 0; j4 < 4; ++j4) {
            bf16x4 pb4;
            #pragma unroll
            for (int e = 0; e < 4; ++e) pb4[e] = (bf16_t)(l[j4 * 4 + e] * inv);
            *(bf16x4*)&Ps[q][kg * 16 + j4 * 4] = pb4;
            *(bf16x4*)(pg + j4 * 4) = pb4;
        }
    }
    __syncthreads();
    // ---- Phase E: PV MFMA
    {
        #pragma unroll
        for (int j = 0; j < 3; ++j) {
            int T = w * 3 + j;
            int m = T & 1, n = T >> 1;
            f32x4 acc = (f32x4){0.f,0.f,0.f,0.f};
            #pragma unroll
            for (int kc = 0; kc < 4; ++kc) {
                bf16x8 a = *(const bf16x8*)&Ps[m*16 + (lane & 15)][kc*32 + (lane >> 4) * 8];
                bf16x8 b = *(const bf16x8*)&Vt[n*16 + (lane & 15)][kc*32 + (lane >> 4) * 8];
                acc = __builtin_amdgcn_mfma_f32_16x16x32_bf16(a, b, acc, 0, 0, 0);
            }
            int rowb = m * 16 + (lane >> 4) * 4;
            int col = lane & 15;
            if (n < 4) {
                #pragma unroll
                for (int i = 0; i < 4; ++i)
                    catb[(size_t)(rowq0 + rowb + i) * CATW + h * 64 + n * 16 + col] = (bf16_t)acc[i];
            } else {
                #pragma unroll
                for (int i = 0; i < 4; ++i)
                    optmp[rowb + i][(n - 4) * 16 + col] = acc[i];
            }
        }
    }
    __syncthreads();
    // ---- Phase F: o_pt inverse transform + norm
    {
        int q = tid >> 3, pp = tid & 7;
        float sx = optmp[q][pp * 3 + 0];
        float sy = optmp[q][pp * 3 + 1];
        float sz = optmp[q][pp * 3 + 2];
        const float* R = rots + (size_t)(rowq0 + q) * 9;
        const float* t = trans + (size_t)(rowq0 + q) * 3;
        float x = sx - t[0], y = sy - t[1], z2 = sz - t[2];
        float ox = R[0] * x + R[3] * y + R[6] * z2;
        float oy = R[1] * x + R[4] * y + R[7] * z2;
        float oz = R[2] * x + R[5] * y + R[8] * z2;
        bf16_t* cp = catb + (size_t)(rowq0 + q) * CATW;
        cp[1024 + h * 24 + pp * 3 + 0] = (bf16_t)ox;
        cp[1024 + h * 24 + pp * 3 + 1] = (bf16_t)oy;
        cp[1024 + h * 24 + pp * 3 + 2] = (bf16_t)oz;
        cp[1408 + h * 8 + pp] = (bf16_t)sqrtf(ox * ox + oy * oy + oz * oz + 1e-8f);
    }
}

// ---------------------------------------------------------------- o_pair: per rowq MFMA [16h x 128k] x [128k x 32c]
__global__ __launch_bounds__(256) void k_opair(const bf16_t* __restrict__ Pbf,
    const bf16_t* __restrict__ pzT, bf16_t* __restrict__ catb)
{
    int tid = threadIdx.x, lane = tid & 63, w = tid >> 6;
    size_t rowq = (size_t)blockIdx.x * 4 + w;
    const bf16_t* Pp = Pbf + rowq * 2048;
    const bf16_t* zp = pzT + rowq * 4096;
    bf16x8 pa[4];
    #pragma unroll
    for (int kc = 0; kc < 4; ++kc)
        pa[kc] = *(const bf16x8*)(Pp + (size_t)(lane & 15) * 128 + kc * 32 + (lane >> 4) * 8);
    #pragma unroll
    for (int ct = 0; ct < 2; ++ct) {
        f32x4 acc = (f32x4){0.f,0.f,0.f,0.f};
        #pragma unroll
        for (int kc = 0; kc < 4; ++kc) {
            bf16x8 b = *(const bf16x8*)(zp + (size_t)(ct * 16 + (lane & 15)) * 128 + kc * 32 + (lane >> 4) * 8);
            acc = __builtin_amdgcn_mfma_f32_16x16x32_bf16(pa[kc], b, acc, 0, 0, 0);
        }
        #pragma unroll
        for (int i = 0; i < 4; ++i) {
            int hh = (lane >> 4) * 4 + i;
            catb[rowq * CATW + 1536 + hh * 32 + ct * 16 + (lane & 15)] = (bf16_t)acc[i];
        }
    }
}

// ---------------------------------------------------------------- out GEMM, 64x128 tile, XCD-friendly flat id
__global__ __launch_bounds__(256) void gemm_out(const bf16_t* __restrict__ A, const bf16_t* __restrict__ BT,
    float* __restrict__ C)
{
    __shared__ bf16_t Asl[64][32];
    __shared__ bf16_t Bsl[128][32];
    const int tid = threadIdx.x, lane = tid & 63, w = tid >> 6;
    const int by = blockIdx.x & 63, bxc = blockIdx.x >> 6;
    const int row0 = by * 64, col0 = bxc * 128;
    const int wr = (w >> 1) * 32, wc = (w & 1) * 64;
    const int K = 2048;
    const int sr = lane >> 2, k8 = (lane & 3) * 8;
    const bf16_t* Ab = A + (size_t)(row0 + w * 16 + sr) * K + k8;
    const bf16_t* Bb = BT + (size_t)(col0 + w * 32 + sr) * K + k8;
    f32x4 acc[2][4];
    #pragma unroll
    for (int m = 0; m < 2; ++m)
        #pragma unroll
        for (int n = 0; n < 4; ++n) acc[m][n] = (f32x4){0.f,0.f,0.f,0.f};
    for (int k0 = 0; k0 < K; k0 += 32) {
        __syncthreads();
        gld16(Ab + k0,          &Asl[w * 16][0]);
        gld16(Bb + k0,          &Bsl[w * 32][0]);
        gld16(Bb + k0 + 16 * K, &Bsl[w * 32 + 16][0]);
        __syncthreads();
        bf16x8 af[2], bfr[4];
        #pragma unroll
        for (int m = 0; m < 2; ++m) af[m]  = *(const bf16x8*)&Asl[wr + m*16 + (lane & 15)][(lane >> 4) * 8];
        #pragma unroll
        for (int n = 0; n < 4; ++n) bfr[n] = *(const bf16x8*)&Bsl[wc + n*16 + (lane & 15)][(lane >> 4) * 8];
        #pragma unroll
        for (int m = 0; m < 2; ++m)
            #pragma unroll
            for (int n = 0; n < 4; ++n)
                acc[m][n] = __builtin_amdgcn_mfma_f32_16x16x32_bf16(af[m], bfr[n], acc[m][n], 0, 0, 0);
    }
    #pragma unroll
    for (int m = 0; m < 2; ++m)
        #pragma unroll
        for (int n = 0; n < 4; ++n)
            #pragma unroll
            for (int i = 0; i < 4; ++i)
                C[(size_t)(row0 + wr + m*16 + (lane >> 4)*4 + i) * 512 + col0 + wc + n*16 + (lane & 15)] = acc[m][n][i];
}

// ---------------------------------------------------------------- launcher
extern "C" void kernel_launch(void* const* d_in, const int* in_sizes, int n_in,
                              void* d_out, int out_size, void* d_ws, size_t ws_size,
                              hipStream_t stream)
{
    (void)in_sizes; (void)n_in; (void)out_size;
    const float* s     = (const float*)d_in[0];
    const float* z     = (const float*)d_in[1];
    const float* trans = (const float*)d_in[2];
    const float* rots  = (const float*)d_in[3];
    const float* smask = (const float*)d_in[4];
    const int*   kidx  = (const int*)d_in[5];
    const float* Wq    = (const float*)d_in[6];
    const float* Wk    = (const float*)d_in[7];
    const float* Wv    = (const float*)d_in[8];
    const float* Wqp   = (const float*)d_in[9];
    const float* Wkvp  = (const float*)d_in[10];
    const float* Wb    = (const float*)d_in[11];
    const float* Wdz   = (const float*)d_in[12];
    const float* hw    = (const float*)d_in[13];
    const float* Wout  = (const float*)d_in[14];
    const float* g_s   = (const float*)d_in[15];
    const float* b_s   = (const float*)d_in[16];
    const float* g_z   = (const float*)d_in[17];
    const float* b_z   = (const float*)d_in[18];

    char* ws = (char*)d_ws;
    bf16_t* projb = (bf16_t*)(ws);                      // 25,165,824
    float*  projp = (float*)(ws + 25165824);            // 12,582,912
    bf16_t* biasT = (bf16_t*)(ws + 37748736);           // 16,777,216 (bf16 now; slot reserves 33 MB)
    bf16_t* wcatT = (bf16_t*)(ws + 71303168);           //  3,932,160
    bf16_t* s_nb  = (bf16_t*)(ws + 75235328);           //  4,194,304
    bf16_t* pzT   = (bf16_t*)(ws + 79429632);           // 33,554,432
    bf16_t* Pbf   = (bf16_t*)(ws + 112984064);          // 16,777,216
    bf16_t* catb  = (bf16_t*)(ws + 129761280);          // 16,777,216
    bf16_t* WoutT = (bf16_t*)(ws + 146538496);          //  2,097,152
    bf16_t* WzT   = (bf16_t*)(ws + 148635648);          //     12,288
    float*  Kv    = (float*)(ws + 148647936);           //        192
    if (ws_size < (size_t)148648128) return;
    float* out = (float*)d_out;

    k_prep<<<1761, 256, 0, stream>>>(Wq, Wk, Wv, Wqp, Wkvp, Wout, Wb, Wdz, g_z, b_z,
                                     s, g_s, b_s, wcatT, WoutT, WzT, Kv, s_nb);
    k_fused<<<3008, 256, 0, stream>>>(s_nb, wcatT, projb, projp, z, WzT, Kv, biasT, pzT);
    k_attn4<<<2048, 256, 0, stream>>>(projb, projp, biasT, rots, trans, smask, kidx, hw, catb, Pbf);
    k_opair<<<1024, 256, 0, stream>>>(Pbf, pzT, catb);
    gemm_out<<<256, 256, 0, stream>>>(catb, WoutT, out);
}